// Round 17
// baseline (1349.164 us; speedup 1.0000x reference)
//
#include <hip/hip_runtime.h>

typedef unsigned char u8;
typedef unsigned short u16;
typedef unsigned int u32;
typedef unsigned long long u64;
typedef long long i64;

#define TT 4
#define PH 4096             // pairs per half
#define KSW 16              // K/32 images for K=512
#define BNEPS 1e-5f

typedef __attribute__((ext_vector_type(8))) __bf16 bf16x8;
typedef __attribute__((ext_vector_type(4))) float f32x4;

__device__ __forceinline__ float bf2f(u16 b){ return __uint_as_float(((u32)b)<<16); }
__device__ __forceinline__ u16 f2bf_rne(float f){ u32 u = __float_as_uint(f); return (u16)((u + 0x7FFFu + ((u>>16)&1u))>>16); }

__device__ __forceinline__ f32x4 MFMA(bf16x8 a, bf16x8 b, f32x4 c){
    return __builtin_amdgcn_mfma_f32_16x16x32_bf16(a, b, c, 0, 0, 0);
}

union BF8 { u16 u[8]; bf16x8 v; };

__device__ __forceinline__ void gload16(const void* g, void* l){
    __builtin_amdgcn_global_load_lds(
        (const __attribute__((address_space(1))) unsigned int*)g,
        (__attribute__((address_space(3))) unsigned int*)l, 16, 0, 0);
}

// reg-staged kernels' swizzles (validated r3-r16)
__device__ __forceinline__ int swz(int row, int off){ return row*64 + (off ^ (((row>>1)&3)<<4)); }
__device__ __forceinline__ int swzK(int row, int off){ return row*128 + (off ^ ((row&7)<<4)); }
__device__ __forceinline__ int swzV(int row, int off){ return row*256 + (off ^ ((row&7)<<4)); }

__device__ __forceinline__ uint4 expand8(const u8* pb){
    u32 w0 = (pb[0]?0x3F80u:0u) | ((pb[1]?0x3F80u:0u)<<16);
    u32 w1 = (pb[2]?0x3F80u:0u) | ((pb[3]?0x3F80u:0u)<<16);
    u32 w2 = (pb[4]?0x3F80u:0u) | ((pb[5]?0x3F80u:0u)<<16);
    u32 w3 = (pb[6]?0x3F80u:0u) | ((pb[7]?0x3F80u:0u)<<16);
    return make_uint4(w0,w1,w2,w3);
}
__device__ __forceinline__ uint4 expandbits(u32 bits){
    u32 w0 = ((bits>>0)&1?0x3F80u:0u) | ((bits>>1)&1?0x3F800000u:0u);
    u32 w1 = ((bits>>2)&1?0x3F80u:0u) | ((bits>>3)&1?0x3F800000u:0u);
    u32 w2 = ((bits>>4)&1?0x3F80u:0u) | ((bits>>5)&1?0x3F800000u:0u);
    u32 w3 = ((bits>>6)&1?0x3F80u:0u) | ((bits>>7)&1?0x3F800000u:0u);
    return make_uint4(w0,w1,w2,w3);
}

// ---------------- W -> CB-col 1-plane RNE images
__global__ __launch_bounds__(256)
void wsplit_rne(const float* __restrict__ W, u8* __restrict__ out, int NC, int nbOff, int ksn, int CB)
{
    const int ks = blockIdx.x, nbl = blockIdx.y;
    const int c0 = nbl*CB;
    u8* img = out + ((i64)(nbOff+nbl)*ksn + ks)*(i64)(CB*64);
    const int iters = CB >> 6;
    for (int it=0; it<iters; it++){
        int task = threadIdx.x + it*256;
        int col = task>>2, gq = task&3;
        float v[8];
        #pragma unroll
        for (int j=0;j<8;j++) v[j] = W[(i64)(ks*32 + gq*8 + j)*NC + c0 + col];
        u16 h[8];
        #pragma unroll
        for (int j=0;j<8;j++) h[j] = f2bf_rne(v[j]);
        int off = gq*(CB*16) + col*16;
        *(ushort4*)(img + off)     = make_ushort4(h[0],h[1],h[2],h[3]);
        *(ushort4*)(img + off + 8) = make_ushort4(h[4],h[5],h[6],h[7]);
    }
}

// ---------------- W -> RNE bf16 [NC][K] (for p reg-staged GEMM)
__global__ __launch_bounds__(256)
void wsplit_old(const float* __restrict__ W, u16* __restrict__ out, int K, int NC)
{
    __shared__ float tile[64][65];
    const int k0 = blockIdx.x*64, c0 = blockIdx.y*64;
    const int tid = threadIdx.x;
    #pragma unroll
    for (int j=0;j<16;j++){
        int el = tid + j*256; int r = el>>6, c = el&63;
        tile[r][c] = W[(i64)(k0+r)*NC + c0 + c];
    }
    __syncthreads();
    #pragma unroll
    for (int j=0;j<16;j++){
        int el = tid + j*256; int c = el>>6, k = el&63;
        out[(i64)(c0+c)*K + k0 + k] = f2bf_rne(tile[k][c]);
    }
}

// ---------------- x -> A images (1-plane RNE): img(pb,ks)[g][row 0..255][16B], row = pair*4+t, 16KB
__global__ __launch_bounds__(256)
void asplitT(const float* __restrict__ x, u8* __restrict__ At, int pairBase)
{
    const int pb = blockIdx.x, ks = blockIdx.y;
    u8* img = At + ((i64)pb*KSW + ks)*16384;
    #pragma unroll
    for (int it=0; it<4; it++){
        int task = threadIdx.x + it*256;
        int row = task>>2, gq = task&3;
        int pair = row>>2, t = row&3;
        i64 grow = (i64)t*8192 + pairBase + pb*64 + pair;
        const float* src = x + grow*512 + ks*32 + gq*8;
        float4 f0 = *(const float4*)src, f1v = *(const float4*)(src+4);
        float vv[8] = {f0.x,f0.y,f0.z,f0.w,f1v.x,f1v.y,f1v.z,f1v.w};
        u16 h[8];
        #pragma unroll
        for (int j=0;j<8;j++) h[j] = f2bf_rne(vv[j]);
        int off = gq*4096 + row*16;
        *(ushort4*)(img + off)     = make_ushort4(h[0],h[1],h[2],h[3]);
        *(ushort4*)(img + off + 8) = make_ushort4(h[4],h[5],h[6],h[7]);
    }
}

// ---------------- gemm8 v5 (1-product RNE(A)*RNE(W)): BM=256 x BN=128,
// dbuf 2x(A 16K + B 8K) = 48KB -> 3 blocks/CU. 8 waves 4Mx2N (wave 64x64), 16 MFMA/tile.
template<bool BITOUT>
__global__ __launch_bounds__(512,6)
void gemm8(const u8* __restrict__ At, const u8* __restrict__ Bt,
           const float* __restrict__ b0, const float* __restrict__ b1, const float* __restrict__ b2,
           const float* __restrict__ g0, const float* __restrict__ g1, const float* __restrict__ g2,
           const float* __restrict__ e0, const float* __restrict__ e1, const float* __restrict__ e2,
           const float* __restrict__ u0, const float* __restrict__ u1, const float* __restrict__ u2,
           const float* __restrict__ v0, const float* __restrict__ v1, const float* __restrict__ v2,
           u8* __restrict__ outp, int NB, int NCT, int cmask)
{
    extern __shared__ __align__(16) char smem[];     // 49152: 2 x (A 16K + B 8K)
    const int tid = threadIdx.x;
    const int cpx = gridDim.x >> 3;
    const int serial = (blockIdx.x & 7)*cpx + (blockIdx.x >> 3);
    const int pb = serial / NB, nb = serial % NB;

    const int w = tid>>6, lane = tid&63, g = lane>>4, ln = lane&15;
    const int wm = w>>1, wn = w&1;                   // 4M x 2N, wave 64x64

    f32x4 acc[4][4];
    #pragma unroll
    for (int fm=0;fm<4;fm++)
        #pragma unroll
        for (int cb=0;cb<4;cb++) acc[fm][cb] = (f32x4)0.f;

    const u8* Ab = At + (i64)pb*KSW*16384;
    const u8* Bb = Bt + (i64)nb*KSW*8192;

    #pragma unroll
    for (int j=0;j<2;j++)
        gload16(Ab + j*8192 + tid*16, smem + j*8192 + tid*16);
    gload16(Bb + tid*16, smem + 16384 + tid*16);
    __syncthreads();

    for (int ks=0; ks<KSW; ks++){
        char* cur = smem + (ks&1)*24576;
        char* nxt = smem + ((ks+1)&1)*24576;
        if (ks+1 < KSW){
            const u8* Ai = Ab + (i64)(ks+1)*16384;
            #pragma unroll
            for (int j=0;j<2;j++) gload16(Ai + j*8192 + tid*16, nxt + j*8192 + tid*16);
            gload16(Bb + (i64)(ks+1)*8192 + tid*16, nxt + 16384 + tid*16);
        }
        bf16x8 bfr[4];
        #pragma unroll
        for (int cb=0;cb<4;cb++){
            int col = wn*64 + cb*16 + ln;
            bfr[cb] = *(const bf16x8*)(cur + 16384 + g*2048 + col*16);
        }
        bf16x8 af[4];
        #pragma unroll
        for (int fm=0; fm<4; fm++){
            int row = wm*64 + fm*16 + ln;
            af[fm] = *(const bf16x8*)(cur + g*4096 + row*16);
        }
        __builtin_amdgcn_s_setprio(1);
        #pragma unroll
        for (int fm=0; fm<4; fm++)
            #pragma unroll
            for (int cb=0;cb<4;cb++)
                acc[fm][cb] = MFMA(af[fm], bfr[cb], acc[fm][cb]);
        __builtin_amdgcn_s_setprio(0);
        __syncthreads();
    }

    if (BITOUT){
        #pragma unroll
        for (int cb=0; cb<4; cb++){
            const int c = nb*128 + wn*64 + cb*16 + ln;
            const float gs  = g0[c & cmask] / sqrtf(v0[c & cmask] + BNEPS);
            const float bf_ = b0[c & cmask], muf = u0[c & cmask], bef = e0[c & cmask];
            #pragma unroll
            for (int fm=0; fm<4; fm++){
                const int prow = pb*64 + wm*16 + fm*4 + g;
                float v = 0.f;
                #pragma unroll
                for (int t=0; t<TT; t++){
                    float y = acc[fm][cb][t] + bf_;
                    float z = (y - muf) * gs + bef;
                    v = v + (z - v) * 0.5f;
                    float s = ((v - 1.0f) >= 0.f) ? 1.f : 0.f;
                    u64 bal = __ballot(s != 0.f);
                    if (ln == 0)
                        *(u16*)(outp + (i64)(t*PH + prow)*(NCT>>3) + ((nb*128 + wn*64 + cb*16)>>3)) = (u16)(bal >> (g*16));
                    v = v * (1.f - s);
                }
            }
        }
    } else {
        // LDS-staged coalesced epilogue: tile [t][64 rows][128 c] u8 = 32KB (fits 48KB)
        u8* tile = (u8*)smem;
        #pragma unroll
        for (int cb=0; cb<4; cb++){
            const int c = nb*128 + wn*64 + cb*16 + ln;
            int which = c >> 9; if (which > 2) which = 2;
            const float* bp = which==0?b0:(which==1?b1:b2);
            const float* gp = which==0?g0:(which==1?g1:g2);
            const float* ep = which==0?e0:(which==1?e1:e2);
            const float* up = which==0?u0:(which==1?u1:u2);
            const float* vp = which==0?v0:(which==1?v1:v2);
            const int ci = c & cmask;
            const float gs  = gp[ci] / sqrtf(vp[ci] + BNEPS);
            const float bf_ = bp[ci], muf = up[ci], bef = ep[ci];
            #pragma unroll
            for (int fm=0; fm<4; fm++){
                const int rowL = wm*16 + fm*4 + g;
                float v = 0.f;
                #pragma unroll
                for (int t=0; t<TT; t++){
                    float y = acc[fm][cb][t] + bf_;
                    float z = (y - muf) * gs + bef;
                    v = v + (z - v) * 0.5f;
                    float s = ((v - 1.0f) >= 0.f) ? 1.f : 0.f;
                    tile[t*8192 + rowL*128 + (wn*64 + cb*16 + ln)] = (u8)s;
                    v = v * (1.f - s);
                }
            }
        }
        __syncthreads();
        #pragma unroll
        for (int it=0; it<4; it++){
            int task = tid + it*512;
            int t = task>>9, row = (task>>3)&63, seg = task&7;
            uint4 d = *(const uint4*)(tile + t*8192 + row*128 + seg*16);
            *(uint4*)(outp + (i64)(t*PH + pb*64 + row)*NCT + nb*128 + seg*16) = d;
        }
    }
}

// ---------------- f2 v4 (r14, kept): BM=128 x BN=256, K=2048, grid 512, T14 staging,
// LDS-transpose coalesced epilogue (float4 x/out, u32 o2).
__global__ __launch_bounds__(512,4)
void gemm8_f2(const u8* __restrict__ hh0, const u8* __restrict__ hh1,
              const u8* __restrict__ Bt,
              const float* __restrict__ bias, const float* __restrict__ gw,
              const float* __restrict__ bew,  const float* __restrict__ muw,
              const float* __restrict__ varw,
              const float* __restrict__ x,
              const u8* __restrict__ o20, const u8* __restrict__ o21,
              float* __restrict__ outF)
{
    __shared__ __align__(16) char smem[49152];
    const int tid = threadIdx.x;
    const int cpx = gridDim.x >> 3;
    const int serial = (blockIdx.x & 7)*cpx + (blockIdx.x >> 3);
    const int nb = serial & 1, pbg = serial >> 1;
    const int half = pbg >> 7, pb = pbg & 127;
    const u8* Abits = half ? hh1 : hh0;
    const u8* o2g   = half ? o21 : o20;

    const int w = tid>>6, lane = tid&63, g = lane>>4, ln = lane&15;
    const int wm = w>>2, wn = w&3;

    f32x4 acc[4][4];
    #pragma unroll
    for (int fm=0;fm<4;fm++)
        #pragma unroll
        for (int cb=0;cb<4;cb++) acc[fm][cb] = (f32x4)0.f;

    const u8* Bb = Bt + (i64)nb*64*16384;
    const int aRow = tid>>2, aGq = tid&3;
    const i64 aGrow = (i64)(aRow&3)*PH + pb*32 + (aRow>>2);

    {
        u32 b40 = *(const u32*)(Abits + aGrow*256);
        *(uint4*)(smem + swz(aRow, aGq*16)) = expandbits(b40 >> (8*aGq));
    }
    #pragma unroll
    for (int j=0;j<2;j++)
        gload16(Bb + (tid + j*512)*16, smem + 8192 + (tid + j*512)*16);
    __syncthreads();

    for (int ks=0; ks<64; ks++){
        char* cur = smem + (ks&1)*24576;
        char* nxt = smem + ((ks+1)&1)*24576;
        const bool pre = (ks+1 < 64);
        u32 b4n = 0;
        if (pre){
            b4n = *(const u32*)(Abits + aGrow*256 + (ks+1)*4);
            #pragma unroll
            for (int j=0;j<2;j++)
                gload16(Bb + (i64)(ks+1)*16384 + (tid+j*512)*16, nxt + 8192 + (tid+j*512)*16);
        }
        bf16x8 bfr[4], af[4];
        #pragma unroll
        for (int cb=0;cb<4;cb++)
            bfr[cb] = *(const bf16x8*)(cur + 8192 + g*4096 + (wn*64 + cb*16 + ln)*16);
        #pragma unroll
        for (int fm=0;fm<4;fm++)
            af[fm] = *(const bf16x8*)(cur + swz(wm*64 + fm*16 + ln, g*16));
        __builtin_amdgcn_s_setprio(1);
        #pragma unroll
        for (int fm=0;fm<4;fm++)
            #pragma unroll
            for (int cb=0;cb<4;cb++)
                acc[fm][cb] = MFMA(af[fm], bfr[cb], acc[fm][cb]);
        __builtin_amdgcn_s_setprio(0);
        if (pre)
            *(uint4*)(nxt + swz(aRow, aGq*16)) = expandbits(b4n >> (8*aGq));
        __syncthreads();
    }

    float gsA[4], bfA[4], muA[4], beA[4];
    #pragma unroll
    for (int cb=0;cb<4;cb++){
        const int c = nb*256 + wn*64 + cb*16 + ln;
        gsA[cb] = gw[c] / sqrtf(varw[c] + BNEPS);
        bfA[cb] = bias[c]; muA[cb] = muw[c]; beA[cb] = bew[c];
    }
    float vst[4][4];
    #pragma unroll
    for (int fm=0;fm<4;fm++)
        #pragma unroll
        for (int cb=0;cb<4;cb++) vst[fm][cb] = 0.f;

    float* ft = (float*)smem;
    for (int t=0; t<TT; t++){
        __syncthreads();
        #pragma unroll
        for (int cb=0;cb<4;cb++)
            #pragma unroll
            for (int fm=0;fm<4;fm++){
                const int rowL = wm*16 + fm*4 + g;
                float y = acc[fm][cb][t] + bfA[cb];
                float z = (y - muA[cb]) * gsA[cb] + beA[cb];
                float v = vst[fm][cb];
                v = v + (z - v) * 0.5f;
                float s = ((v - 1.0f) >= 0.f) ? 1.f : 0.f;
                ft[rowL*264 + wn*64 + cb*16 + ln] = s;
                vst[fm][cb] = v * (1.f - s);
            }
        __syncthreads();
        #pragma unroll
        for (int it=0; it<4; it++){
            int task = tid + it*512;
            int rowL = task>>6, seg = task&63;
            float4 sv = *(const float4*)(ft + rowL*264 + seg*4);
            i64 grow = (i64)t*8192 + half*PH + pb*32 + rowL;
            i64 lrow = (i64)t*PH + pb*32 + rowL;
            const int cg = nb*256 + seg*4;
            float4 xv = *(const float4*)(x + grow*512 + cg);
            u32 o4 = *(const u32*)(o2g + lrow*512 + cg);
            float4 r;
            r.x = (xv.x + (float)( o4      &255u)) + sv.x;
            r.y = (xv.y + (float)((o4>> 8) &255u)) + sv.y;
            r.z = (xv.z + (float)((o4>>16) &255u)) + sv.z;
            r.w = (xv.w + (float)((o4>>24) &255u)) + sv.w;
            *(float4*)(outF + grow*512 + cg) = r;
        }
    }
}

// ---------------- p stage: spikes x W GEMM + BN + LIF -> o2 (global) + f1 A-images (RNE(x+o2))
__global__ __launch_bounds__(256)
void gemm_p(const u8* __restrict__ Au8, const u16* __restrict__ WT,
            const float* __restrict__ bias, const float* __restrict__ gw,
            const float* __restrict__ bew,  const float* __restrict__ muw,
            const float* __restrict__ varw,
            const float* __restrict__ x, u8* __restrict__ o2g,
            u8* __restrict__ At, int pairBase)
{
    __shared__ __align__(16) char smem[16384];
    char* smA = smem;
    char* smB = smem + 8192;
    const int tid = threadIdx.x;
    const int nbp = blockIdx.x, pbp = blockIdx.y;
    const int c0 = nbp*128, pair0 = pbp*32;
    const int w = tid>>6, l = tid&63, g = l>>4, ln = l&15;
    const int wm = w>>1, wn = w&1;

    f32x4 acc[TT][4];
    #pragma unroll
    for (int t=0;t<TT;t++)
        #pragma unroll
        for (int cf=0;cf<4;cf++) acc[t][cf] = (f32x4)0.f;

    for (int k0 = 0; k0 < 512; k0 += 32){
        __syncthreads();
        {
            const int row = tid>>1, half = tid&1;
            const int t = row>>5, pp = row&31;
            const i64 grow = (i64)t*PH + pair0 + pp;
            uint4 ob = *(const uint4*)(Au8 + grow*512 + k0 + half*16);
            const u8* pbb = (const u8*)&ob;
            *(uint4*)(smA + swz(row, half*32))    = expand8(pbb);
            *(uint4*)(smA + swz(row, half*32+16)) = expand8(pbb+8);
        }
        #pragma unroll
        for (int j=0;j<2;j++){
            int cid = tid + j*256;
            int col = cid>>2, c = cid&3;
            uint4 d = *(const uint4*)(WT + (i64)(c0+col)*512 + k0 + c*8);
            *(uint4*)(smB + swz(col, c*16)) = d;
        }
        __syncthreads();
        bf16x8 bfr[4];
        #pragma unroll
        for (int cf=0;cf<4;cf++)
            bfr[cf] = *(const bf16x8*)(smB + swz(wn*64 + cf*16 + ln, g*16));
        #pragma unroll
        for (int t=0;t<TT;t++){
            bf16x8 afr = *(const bf16x8*)(smA + swz(t*32 + wm*16 + ln, g*16));
            #pragma unroll
            for (int cf=0;cf<4;cf++)
                acc[t][cf] = MFMA(afr, bfr[cf], acc[t][cf]);
        }
    }

    __syncthreads();
    u8* tile = (u8*)smem;
    #pragma unroll
    for (int cf=0;cf<4;cf++){
        const int c = c0 + wn*64 + cf*16 + ln;
        const float gs  = gw[c] / sqrtf(varw[c] + BNEPS);
        const float bf_ = bias[c], muf = muw[c], bef = bew[c];
        #pragma unroll
        for (int r=0;r<4;r++){
            const int rl = wm*16 + g*4 + r;
            float v = 0.f;
            #pragma unroll
            for (int t=0;t<TT;t++){
                float y = acc[t][cf][r] + bf_;
                float z = (y - muf) * gs + bef;
                v = v + (z - v) * 0.5f;
                float s = ((v - 1.0f) >= 0.f) ? 1.f : 0.f;
                tile[t*4096 + rl*128 + (wn*64 + cf*16 + ln)] = (u8)s;
                v = v * (1.f - s);
            }
        }
    }
    __syncthreads();

    const int pbImg = pbp>>1, rOff = (pbp&1)*128;
    #pragma unroll
    for (int it=0; it<8; it++){
        int task = tid + it*256;
        int kq = task>>9, rem = task&511, gq = rem>>7, rowL = rem&127;
        int rl = rowL>>2, t = rowL&3;
        int ksAbs = nbp*4 + kq;
        int cL = kq*32 + gq*8;
        uint2 ob = *(const uint2*)(tile + t*4096 + rl*128 + cL);
        const u8* pbb = (const u8*)&ob;
        i64 grow = (i64)t*8192 + pairBase + pair0 + rl;
        const float* src = x + grow*512 + ksAbs*32 + gq*8;
        float4 f0 = *(const float4*)src, f1v = *(const float4*)(src+4);
        float vv[8] = {f0.x,f0.y,f0.z,f0.w,f1v.x,f1v.y,f1v.z,f1v.w};
        #pragma unroll
        for (int j=0;j<8;j++) vv[j] = vv[j] + (float)pbb[j];
        u16 h[8];
        #pragma unroll
        for (int j=0;j<8;j++) h[j] = f2bf_rne(vv[j]);
        u8* img = At + ((i64)pbImg*KSW + ksAbs)*16384;
        int off = gq*4096 + (rOff + rowL)*16;
        *(ushort4*)(img + off)     = make_ushort4(h[0],h[1],h[2],h[3]);
        *(ushort4*)(img + off + 8) = make_ushort4(h[4],h[5],h[6],h[7]);
        *(uint2*)(o2g + ((i64)t*PH + pair0 + rl)*512 + ksAbs*32 + gq*8) = ob;
    }
}

// ---------------- spiking attention + attn-LIF (v_th=0.5), qkv packed stride 1536
__global__ __launch_bounds__(256)
void attn_lif_kernel(const u8* __restrict__ qkv, u8* __restrict__ os)
{
    __shared__ __align__(16) char smem[49152];
    char* Kl = smem;
    char* VT = smem + 16384;
    char* AT = smem + 32768;

    const int tid = threadIdx.x;
    const int w = tid>>6, l = tid&63, g = l>>4, ln = l&15;
    const int h = blockIdx.y, b = blockIdx.z;
    const int n0 = blockIdx.x*64 + w*16;

    f32x4 vmem[4];
    #pragma unroll
    for (int cf=0;cf<4;cf++) vmem[cf] = (f32x4)0.f;

    for (int t=0;t<TT;t++){
        const i64 tb = ((i64)(t*16 + b)*256)*1536;
        const i64 ob = ((i64)(t*16 + b)*256)*512 + h*64;
        bf16x8 qf[2];
        #pragma unroll
        for (int ksl=0;ksl<2;ksl++){
            uint2 qv = *(const uint2*)(qkv + tb + (i64)(n0+ln)*1536 + h*64 + ksl*32 + g*8);
            const u8* pb = (const u8*)&qv;
            BF8 f;
            #pragma unroll
            for (int j=0;j<8;j++) f.u[j] = pb[j] ? 0x3F80 : 0;
            qf[ksl] = f.v;
        }
        f32x4 oacc[4];
        #pragma unroll
        for (int cf=0;cf<4;cf++) oacc[cf] = (f32x4)0.f;

        for (int mh=0; mh<2; mh++){
            __syncthreads();
            {
                const int lm = tid>>1, seg = tid&1;
                const u8* src = qkv + tb + (i64)(mh*128+lm)*1536 + 512 + h*64 + seg*32;
                uint4 a = *(const uint4*)(src), c = *(const uint4*)(src+16);
                const u8* pa = (const u8*)&a; const u8* pc = (const u8*)&c;
                #pragma unroll
                for (int q=0;q<4;q++){
                    *(ushort4*)(Kl + swzK(lm, seg*64 + q*8)) =
                        make_ushort4(pa[q*4]?0x3F80:0, pa[q*4+1]?0x3F80:0, pa[q*4+2]?0x3F80:0, pa[q*4+3]?0x3F80:0);
                    *(ushort4*)(Kl + swzK(lm, seg*64 + 32 + q*8)) =
                        make_ushort4(pc[q*4]?0x3F80:0, pc[q*4+1]?0x3F80:0, pc[q*4+2]?0x3F80:0, pc[q*4+3]?0x3F80:0);
                }
            }
            {
                const int lm = tid>>1, seg = tid&1;
                const u8* src = qkv + tb + (i64)(mh*128+lm)*1536 + 1024 + h*64 + seg*32;
                uint4 a = *(const uint4*)(src), c = *(const uint4*)(src+16);
                const u8* pa = (const u8*)&a; const u8* pc = (const u8*)&c;
                #pragma unroll
                for (int j=0;j<16;j++){
                    *(u16*)(VT + swzV(seg*32 + j,      lm*2)) = pa[j] ? 0x3F80 : 0;
                    *(u16*)(VT + swzV(seg*32 + 16 + j, lm*2)) = pc[j] ? 0x3F80 : 0;
                }
            }
            __syncthreads();
            #pragma unroll
            for (int rf=0;rf<8;rf++){
                f32x4 s = (f32x4)0.f;
                #pragma unroll
                for (int ksl=0;ksl<2;ksl++){
                    bf16x8 kf = *(const bf16x8*)(Kl + swzK(rf*16+ln, ksl*64 + g*16));
                    s = MFMA(kf, qf[ksl], s);
                }
                ushort4 pk = make_ushort4(f2bf_rne(s[0]*0.125f), f2bf_rne(s[1]*0.125f),
                                          f2bf_rne(s[2]*0.125f), f2bf_rne(s[3]*0.125f));
                *(ushort4*)(AT + swzV(w*16+ln, rf*32 + g*8)) = pk;
            }
            #pragma unroll
            for (int ms=0;ms<4;ms++){
                bf16x8 af = *(const bf16x8*)(AT + swzV(w*16+ln, ms*64 + g*16));
                #pragma unroll
                for (int cf=0;cf<4;cf++){
                    bf16x8 vf = *(const bf16x8*)(VT + swzV(cf*16+ln, ms*64 + g*16));
                    oacc[cf] = MFMA(af, vf, oacc[cf]);
                }
            }
        }
        #pragma unroll
        for (int cf=0;cf<4;cf++)
            #pragma unroll
            for (int r=0;r<4;r++){
                float v = vmem[cf][r];
                v = v + (oacc[cf][r] - v) * 0.5f;
                float s = ((v - 0.5f) >= 0.f) ? 1.f : 0.f;
                os[ob + (i64)(n0 + g*4 + r)*512 + cf*16 + ln] = (u8)s;
                vmem[cf][r] = v * (1.f - s);
            }
    }
}

extern "C" void kernel_launch(void* const* d_in, const int* in_sizes, int n_in,
                              void* d_out, int out_size, void* d_ws, size_t ws_size,
                              hipStream_t stream)
{
    (void)in_sizes; (void)n_in; (void)out_size; (void)ws_size;
    const float* x = (const float*)d_in[0];
    #define GETP(i) ((const float*)d_in[i])

    char* ws = (char*)d_ws;
    u8*  Bqkv = (u8*)(ws + 0);               // 12*16*8192 = 1,572,864
    u8*  Bf1  = (u8*)(ws + 1572864);         // 16*16*8192 = 2,097,152
    u8*  Bf2  = (u8*)(ws + 3670016);         //  2*64*16384 = 2,097,152
    u16* WTp  = (u16*)(ws + 5767168);        //  524,288
    u8*  At   = (u8*)(ws + 6291456);         // 64*16*16384 = 16,777,216
    u8*  qkv  = (u8*)(ws + 23068672);        // 25,165,824
    u8*  os_  = (u8*)(ws + 48234496);        //  8,388,608
    u8*  o2h[2] = { (u8*)(ws + 56623104), (u8*)(ws + 65011712) };   // 8,388,608 each
    u8*  hhb[2] = { (u8*)(ws + 73400320), (u8*)(ws + 77594624) };   // 4,194,304 each -> ends 81,788,928

    hipFuncSetAttribute((const void*)gemm8<false>, hipFuncAttributeMaxDynamicSharedMemorySize, 49152);
    hipFuncSetAttribute((const void*)gemm8<true>,  hipFuncAttributeMaxDynamicSharedMemorySize, 49152);

    dim3 blk(256,1,1);
    // W prep: qkv/f1 use 128-col images; f2 keeps 256-col
    wsplit_rne<<<dim3(16,4), blk,0,stream>>>(GETP(1),  Bqkv, 512, 0, 16, 128);
    wsplit_rne<<<dim3(16,4), blk,0,stream>>>(GETP(7),  Bqkv, 512, 4, 16, 128);
    wsplit_rne<<<dim3(16,4), blk,0,stream>>>(GETP(13), Bqkv, 512, 8, 16, 128);
    wsplit_rne<<<dim3(16,16),blk,0,stream>>>(GETP(25), Bf1, 2048, 0, 16, 128);
    wsplit_rne<<<dim3(64,2), blk,0,stream>>>(GETP(31), Bf2,  512, 0, 64, 256);
    wsplit_old<<<dim3(8,8),  blk,0,stream>>>(GETP(19), WTp,  512, 512);

    for (int hb = 0; hb < 2; hb++){
        const int pb = hb * PH;
        asplitT<<<dim3(64,16),blk,0,stream>>>(x, At, pb);
        // fused q/k/v (N=1536, NB=12, grid 768)
        gemm8<false><<<dim3(768),dim3(512),49152,stream>>>(At, Bqkv,
            GETP(2),GETP(8),GETP(14),  GETP(3),GETP(9),GETP(15),
            GETP(4),GETP(10),GETP(16), GETP(5),GETP(11),GETP(17),
            GETP(6),GETP(12),GETP(18), qkv, 12, 1536, 511);
        attn_lif_kernel<<<dim3(4,8,16),blk,0,stream>>>(qkv, os_);
        // p stage + fused o2/f1-image production
        gemm_p<<<dim3(4,128),blk,0,stream>>>(os_, WTp,
            GETP(20),GETP(21),GETP(22),GETP(23),GETP(24), x, o2h[hb], At, pb);
        // f1 (N=2048, NB=16, grid 1024, bitpacked out)
        gemm8<true><<<dim3(1024),dim3(512),49152,stream>>>(At, Bf1,
            GETP(26),GETP(26),GETP(26), GETP(27),GETP(27),GETP(27),
            GETP(28),GETP(28),GETP(28), GETP(29),GETP(29),GETP(29),
            GETP(30),GETP(30),GETP(30), hhb[hb], 16, 2048, 2047);
    }
    // f2 v4: both halves, grid 512, T14 staging, coalesced epilogue -> d_out
    gemm8_f2<<<dim3(512),dim3(512),0,stream>>>(hhb[0], hhb[1], Bf2,
        GETP(32),GETP(33),GETP(34),GETP(35),GETP(36), x, o2h[0], o2h[1], (float*)d_out);
}

// Round 18
// 408.778 us; speedup vs baseline: 3.3005x; 3.3005x over previous
//
#include <hip/hip_runtime.h>

typedef unsigned char u8;
typedef unsigned short u16;
typedef unsigned int u32;
typedef unsigned long long u64;
typedef long long i64;

#define TT 4
#define PH 4096             // pairs per half
#define KSW 16              // K/32 images for K=512
#define BNEPS 1e-5f

typedef __attribute__((ext_vector_type(8))) __bf16 bf16x8;
typedef __attribute__((ext_vector_type(4))) float f32x4;

__device__ __forceinline__ float bf2f(u16 b){ return __uint_as_float(((u32)b)<<16); }
__device__ __forceinline__ u16 f2bf_rne(float f){ u32 u = __float_as_uint(f); return (u16)((u + 0x7FFFu + ((u>>16)&1u))>>16); }

__device__ __forceinline__ f32x4 MFMA(bf16x8 a, bf16x8 b, f32x4 c){
    return __builtin_amdgcn_mfma_f32_16x16x32_bf16(a, b, c, 0, 0, 0);
}

union BF8 { u16 u[8]; bf16x8 v; };

__device__ __forceinline__ void gload16(const void* g, void* l){
    __builtin_amdgcn_global_load_lds(
        (const __attribute__((address_space(1))) unsigned int*)g,
        (__attribute__((address_space(3))) unsigned int*)l, 16, 0, 0);
}

// reg-staged kernels' swizzles (validated r3-r17)
__device__ __forceinline__ int swz(int row, int off){ return row*64 + (off ^ (((row>>1)&3)<<4)); }
__device__ __forceinline__ int swzK(int row, int off){ return row*128 + (off ^ ((row&7)<<4)); }
__device__ __forceinline__ int swzV(int row, int off){ return row*256 + (off ^ ((row&7)<<4)); }

__device__ __forceinline__ uint4 expand8(const u8* pb){
    u32 w0 = (pb[0]?0x3F80u:0u) | ((pb[1]?0x3F80u:0u)<<16);
    u32 w1 = (pb[2]?0x3F80u:0u) | ((pb[3]?0x3F80u:0u)<<16);
    u32 w2 = (pb[4]?0x3F80u:0u) | ((pb[5]?0x3F80u:0u)<<16);
    u32 w3 = (pb[6]?0x3F80u:0u) | ((pb[7]?0x3F80u:0u)<<16);
    return make_uint4(w0,w1,w2,w3);
}
__device__ __forceinline__ uint4 expandbits(u32 bits){
    u32 w0 = ((bits>>0)&1?0x3F80u:0u) | ((bits>>1)&1?0x3F800000u:0u);
    u32 w1 = ((bits>>2)&1?0x3F80u:0u) | ((bits>>3)&1?0x3F800000u:0u);
    u32 w2 = ((bits>>4)&1?0x3F80u:0u) | ((bits>>5)&1?0x3F800000u:0u);
    u32 w3 = ((bits>>6)&1?0x3F80u:0u) | ((bits>>7)&1?0x3F800000u:0u);
    return make_uint4(w0,w1,w2,w3);
}

// ---------------- W -> CB-col 1-plane RNE images
__global__ __launch_bounds__(256)
void wsplit_rne(const float* __restrict__ W, u8* __restrict__ out, int NC, int nbOff, int ksn, int CB)
{
    const int ks = blockIdx.x, nbl = blockIdx.y;
    const int c0 = nbl*CB;
    u8* img = out + ((i64)(nbOff+nbl)*ksn + ks)*(i64)(CB*64);
    const int iters = CB >> 6;
    for (int it=0; it<iters; it++){
        int task = threadIdx.x + it*256;
        int col = task>>2, gq = task&3;
        float v[8];
        #pragma unroll
        for (int j=0;j<8;j++) v[j] = W[(i64)(ks*32 + gq*8 + j)*NC + c0 + col];
        u16 h[8];
        #pragma unroll
        for (int j=0;j<8;j++) h[j] = f2bf_rne(v[j]);
        int off = gq*(CB*16) + col*16;
        *(ushort4*)(img + off)     = make_ushort4(h[0],h[1],h[2],h[3]);
        *(ushort4*)(img + off + 8) = make_ushort4(h[4],h[5],h[6],h[7]);
    }
}

// ---------------- W -> RNE bf16 [NC][K] (for p reg-staged GEMM)
__global__ __launch_bounds__(256)
void wsplit_old(const float* __restrict__ W, u16* __restrict__ out, int K, int NC)
{
    __shared__ float tile[64][65];
    const int k0 = blockIdx.x*64, c0 = blockIdx.y*64;
    const int tid = threadIdx.x;
    #pragma unroll
    for (int j=0;j<16;j++){
        int el = tid + j*256; int r = el>>6, c = el&63;
        tile[r][c] = W[(i64)(k0+r)*NC + c0 + c];
    }
    __syncthreads();
    #pragma unroll
    for (int j=0;j<16;j++){
        int el = tid + j*256; int c = el>>6, k = el&63;
        out[(i64)(c0+c)*K + k0 + k] = f2bf_rne(tile[k][c]);
    }
}

// ---------------- x -> A images (1-plane RNE): img(pb,ks)[g][row 0..255][16B], row = pair*4+t, 16KB
__global__ __launch_bounds__(256)
void asplitT(const float* __restrict__ x, u8* __restrict__ At, int pairBase)
{
    const int pb = blockIdx.x, ks = blockIdx.y;
    u8* img = At + ((i64)pb*KSW + ks)*16384;
    #pragma unroll
    for (int it=0; it<4; it++){
        int task = threadIdx.x + it*256;
        int row = task>>2, gq = task&3;
        int pair = row>>2, t = row&3;
        i64 grow = (i64)t*8192 + pairBase + pb*64 + pair;
        const float* src = x + grow*512 + ks*32 + gq*8;
        float4 f0 = *(const float4*)src, f1v = *(const float4*)(src+4);
        float vv[8] = {f0.x,f0.y,f0.z,f0.w,f1v.x,f1v.y,f1v.z,f1v.w};
        u16 h[8];
        #pragma unroll
        for (int j=0;j<8;j++) h[j] = f2bf_rne(vv[j]);
        int off = gq*4096 + row*16;
        *(ushort4*)(img + off)     = make_ushort4(h[0],h[1],h[2],h[3]);
        *(ushort4*)(img + off + 8) = make_ushort4(h[4],h[5],h[6],h[7]);
    }
}

// ---------------- gemm8 v5 (1-product RNE(A)*RNE(W)): BM=256 x BN=128,
// dbuf 2x(A 16K + B 8K) = 48KB -> 3 blocks/CU (LDS-limited). 8 waves 4Mx2N, 16 MFMA/tile.
template<bool BITOUT>
__global__ __launch_bounds__(512,4)
void gemm8(const u8* __restrict__ At, const u8* __restrict__ Bt,
           const float* __restrict__ b0, const float* __restrict__ b1, const float* __restrict__ b2,
           const float* __restrict__ g0, const float* __restrict__ g1, const float* __restrict__ g2,
           const float* __restrict__ e0, const float* __restrict__ e1, const float* __restrict__ e2,
           const float* __restrict__ u0, const float* __restrict__ u1, const float* __restrict__ u2,
           const float* __restrict__ v0, const float* __restrict__ v1, const float* __restrict__ v2,
           u8* __restrict__ outp, int NB, int NCT, int cmask)
{
    extern __shared__ __align__(16) char smem[];     // 49152: 2 x (A 16K + B 8K)
    const int tid = threadIdx.x;
    const int cpx = gridDim.x >> 3;
    const int serial = (blockIdx.x & 7)*cpx + (blockIdx.x >> 3);
    const int pb = serial / NB, nb = serial % NB;

    const int w = tid>>6, lane = tid&63, g = lane>>4, ln = lane&15;
    const int wm = w>>1, wn = w&1;                   // 4M x 2N, wave 64x64

    f32x4 acc[4][4];
    #pragma unroll
    for (int fm=0;fm<4;fm++)
        #pragma unroll
        for (int cb=0;cb<4;cb++) acc[fm][cb] = (f32x4)0.f;

    const u8* Ab = At + (i64)pb*KSW*16384;
    const u8* Bb = Bt + (i64)nb*KSW*8192;

    #pragma unroll
    for (int j=0;j<2;j++)
        gload16(Ab + j*8192 + tid*16, smem + j*8192 + tid*16);
    gload16(Bb + tid*16, smem + 16384 + tid*16);
    __syncthreads();

    for (int ks=0; ks<KSW; ks++){
        char* cur = smem + (ks&1)*24576;
        char* nxt = smem + ((ks+1)&1)*24576;
        if (ks+1 < KSW){
            const u8* Ai = Ab + (i64)(ks+1)*16384;
            #pragma unroll
            for (int j=0;j<2;j++) gload16(Ai + j*8192 + tid*16, nxt + j*8192 + tid*16);
            gload16(Bb + (i64)(ks+1)*8192 + tid*16, nxt + 16384 + tid*16);
        }
        bf16x8 bfr[4];
        #pragma unroll
        for (int cb=0;cb<4;cb++){
            int col = wn*64 + cb*16 + ln;
            bfr[cb] = *(const bf16x8*)(cur + 16384 + g*2048 + col*16);
        }
        bf16x8 af[4];
        #pragma unroll
        for (int fm=0; fm<4; fm++){
            int row = wm*64 + fm*16 + ln;
            af[fm] = *(const bf16x8*)(cur + g*4096 + row*16);
        }
        __builtin_amdgcn_s_setprio(1);
        #pragma unroll
        for (int fm=0; fm<4; fm++)
            #pragma unroll
            for (int cb=0;cb<4;cb++)
                acc[fm][cb] = MFMA(af[fm], bfr[cb], acc[fm][cb]);
        __builtin_amdgcn_s_setprio(0);
        __syncthreads();
    }

    if (BITOUT){
        #pragma unroll
        for (int cb=0; cb<4; cb++){
            const int c = nb*128 + wn*64 + cb*16 + ln;
            const float gs  = g0[c & cmask] / sqrtf(v0[c & cmask] + BNEPS);
            const float bf_ = b0[c & cmask], muf = u0[c & cmask], bef = e0[c & cmask];
            #pragma unroll
            for (int fm=0; fm<4; fm++){
                const int prow = pb*64 + wm*16 + fm*4 + g;
                float v = 0.f;
                #pragma unroll
                for (int t=0; t<TT; t++){
                    float y = acc[fm][cb][t] + bf_;
                    float z = (y - muf) * gs + bef;
                    v = v + (z - v) * 0.5f;
                    float s = ((v - 1.0f) >= 0.f) ? 1.f : 0.f;
                    u64 bal = __ballot(s != 0.f);
                    if (ln == 0)
                        *(u16*)(outp + (i64)(t*PH + prow)*(NCT>>3) + ((nb*128 + wn*64 + cb*16)>>3)) = (u16)(bal >> (g*16));
                    v = v * (1.f - s);
                }
            }
        }
    } else {
        // LDS-staged coalesced epilogue: tile [t][64 rows][128 c] u8 = 32KB (fits 48KB)
        u8* tile = (u8*)smem;
        #pragma unroll
        for (int cb=0; cb<4; cb++){
            const int c = nb*128 + wn*64 + cb*16 + ln;
            int which = c >> 9; if (which > 2) which = 2;
            const float* bp = which==0?b0:(which==1?b1:b2);
            const float* gp = which==0?g0:(which==1?g1:g2);
            const float* ep = which==0?e0:(which==1?e1:e2);
            const float* up = which==0?u0:(which==1?u1:u2);
            const float* vp = which==0?v0:(which==1?v1:v2);
            const int ci = c & cmask;
            const float gs  = gp[ci] / sqrtf(vp[ci] + BNEPS);
            const float bf_ = bp[ci], muf = up[ci], bef = ep[ci];
            #pragma unroll
            for (int fm=0; fm<4; fm++){
                const int rowL = wm*16 + fm*4 + g;
                float v = 0.f;
                #pragma unroll
                for (int t=0; t<TT; t++){
                    float y = acc[fm][cb][t] + bf_;
                    float z = (y - muf) * gs + bef;
                    v = v + (z - v) * 0.5f;
                    float s = ((v - 1.0f) >= 0.f) ? 1.f : 0.f;
                    tile[t*8192 + rowL*128 + (wn*64 + cb*16 + ln)] = (u8)s;
                    v = v * (1.f - s);
                }
            }
        }
        __syncthreads();
        #pragma unroll
        for (int it=0; it<4; it++){
            int task = tid + it*512;
            int t = task>>9, row = (task>>3)&63, seg = task&7;
            uint4 d = *(const uint4*)(tile + t*8192 + row*128 + seg*16);
            *(uint4*)(outp + (i64)(t*PH + pb*64 + row)*NCT + nb*128 + seg*16) = d;
        }
    }
}

// ---------------- f2 v4 (r14, kept): BM=128 x BN=256, K=2048, grid 512, T14 staging,
// LDS-transpose coalesced epilogue (float4 x/out, u32 o2).
__global__ __launch_bounds__(512,4)
void gemm8_f2(const u8* __restrict__ hh0, const u8* __restrict__ hh1,
              const u8* __restrict__ Bt,
              const float* __restrict__ bias, const float* __restrict__ gw,
              const float* __restrict__ bew,  const float* __restrict__ muw,
              const float* __restrict__ varw,
              const float* __restrict__ x,
              const u8* __restrict__ o20, const u8* __restrict__ o21,
              float* __restrict__ outF)
{
    __shared__ __align__(16) char smem[49152];
    const int tid = threadIdx.x;
    const int cpx = gridDim.x >> 3;
    const int serial = (blockIdx.x & 7)*cpx + (blockIdx.x >> 3);
    const int nb = serial & 1, pbg = serial >> 1;
    const int half = pbg >> 7, pb = pbg & 127;
    const u8* Abits = half ? hh1 : hh0;
    const u8* o2g   = half ? o21 : o20;

    const int w = tid>>6, lane = tid&63, g = lane>>4, ln = lane&15;
    const int wm = w>>2, wn = w&3;

    f32x4 acc[4][4];
    #pragma unroll
    for (int fm=0;fm<4;fm++)
        #pragma unroll
        for (int cb=0;cb<4;cb++) acc[fm][cb] = (f32x4)0.f;

    const u8* Bb = Bt + (i64)nb*64*16384;
    const int aRow = tid>>2, aGq = tid&3;
    const i64 aGrow = (i64)(aRow&3)*PH + pb*32 + (aRow>>2);

    {
        u32 b40 = *(const u32*)(Abits + aGrow*256);
        *(uint4*)(smem + swz(aRow, aGq*16)) = expandbits(b40 >> (8*aGq));
    }
    #pragma unroll
    for (int j=0;j<2;j++)
        gload16(Bb + (tid + j*512)*16, smem + 8192 + (tid + j*512)*16);
    __syncthreads();

    for (int ks=0; ks<64; ks++){
        char* cur = smem + (ks&1)*24576;
        char* nxt = smem + ((ks+1)&1)*24576;
        const bool pre = (ks+1 < 64);
        u32 b4n = 0;
        if (pre){
            b4n = *(const u32*)(Abits + aGrow*256 + (ks+1)*4);
            #pragma unroll
            for (int j=0;j<2;j++)
                gload16(Bb + (i64)(ks+1)*16384 + (tid+j*512)*16, nxt + 8192 + (tid+j*512)*16);
        }
        bf16x8 bfr[4], af[4];
        #pragma unroll
        for (int cb=0;cb<4;cb++)
            bfr[cb] = *(const bf16x8*)(cur + 8192 + g*4096 + (wn*64 + cb*16 + ln)*16);
        #pragma unroll
        for (int fm=0;fm<4;fm++)
            af[fm] = *(const bf16x8*)(cur + swz(wm*64 + fm*16 + ln, g*16));
        __builtin_amdgcn_s_setprio(1);
        #pragma unroll
        for (int fm=0;fm<4;fm++)
            #pragma unroll
            for (int cb=0;cb<4;cb++)
                acc[fm][cb] = MFMA(af[fm], bfr[cb], acc[fm][cb]);
        __builtin_amdgcn_s_setprio(0);
        if (pre)
            *(uint4*)(nxt + swz(aRow, aGq*16)) = expandbits(b4n >> (8*aGq));
        __syncthreads();
    }

    float gsA[4], bfA[4], muA[4], beA[4];
    #pragma unroll
    for (int cb=0;cb<4;cb++){
        const int c = nb*256 + wn*64 + cb*16 + ln;
        gsA[cb] = gw[c] / sqrtf(varw[c] + BNEPS);
        bfA[cb] = bias[c]; muA[cb] = muw[c]; beA[cb] = bew[c];
    }
    float vst[4][4];
    #pragma unroll
    for (int fm=0;fm<4;fm++)
        #pragma unroll
        for (int cb=0;cb<4;cb++) vst[fm][cb] = 0.f;

    float* ft = (float*)smem;
    for (int t=0; t<TT; t++){
        __syncthreads();
        #pragma unroll
        for (int cb=0;cb<4;cb++)
            #pragma unroll
            for (int fm=0;fm<4;fm++){
                const int rowL = wm*16 + fm*4 + g;
                float y = acc[fm][cb][t] + bfA[cb];
                float z = (y - muA[cb]) * gsA[cb] + beA[cb];
                float v = vst[fm][cb];
                v = v + (z - v) * 0.5f;
                float s = ((v - 1.0f) >= 0.f) ? 1.f : 0.f;
                ft[rowL*264 + wn*64 + cb*16 + ln] = s;
                vst[fm][cb] = v * (1.f - s);
            }
        __syncthreads();
        #pragma unroll
        for (int it=0; it<4; it++){
            int task = tid + it*512;
            int rowL = task>>6, seg = task&63;
            float4 sv = *(const float4*)(ft + rowL*264 + seg*4);
            i64 grow = (i64)t*8192 + half*PH + pb*32 + rowL;
            i64 lrow = (i64)t*PH + pb*32 + rowL;
            const int cg = nb*256 + seg*4;
            float4 xv = *(const float4*)(x + grow*512 + cg);
            u32 o4 = *(const u32*)(o2g + lrow*512 + cg);
            float4 r;
            r.x = (xv.x + (float)( o4      &255u)) + sv.x;
            r.y = (xv.y + (float)((o4>> 8) &255u)) + sv.y;
            r.z = (xv.z + (float)((o4>>16) &255u)) + sv.z;
            r.w = (xv.w + (float)((o4>>24) &255u)) + sv.w;
            *(float4*)(outF + grow*512 + cg) = r;
        }
    }
}

// ---------------- p stage: spikes x W GEMM + BN + LIF -> o2 (global) + f1 A-images (RNE(x+o2))
__global__ __launch_bounds__(256)
void gemm_p(const u8* __restrict__ Au8, const u16* __restrict__ WT,
            const float* __restrict__ bias, const float* __restrict__ gw,
            const float* __restrict__ bew,  const float* __restrict__ muw,
            const float* __restrict__ varw,
            const float* __restrict__ x, u8* __restrict__ o2g,
            u8* __restrict__ At, int pairBase)
{
    __shared__ __align__(16) char smem[16384];
    char* smA = smem;
    char* smB = smem + 8192;
    const int tid = threadIdx.x;
    const int nbp = blockIdx.x, pbp = blockIdx.y;
    const int c0 = nbp*128, pair0 = pbp*32;
    const int w = tid>>6, l = tid&63, g = l>>4, ln = l&15;
    const int wm = w>>1, wn = w&1;

    f32x4 acc[TT][4];
    #pragma unroll
    for (int t=0;t<TT;t++)
        #pragma unroll
        for (int cf=0;cf<4;cf++) acc[t][cf] = (f32x4)0.f;

    for (int k0 = 0; k0 < 512; k0 += 32){
        __syncthreads();
        {
            const int row = tid>>1, half = tid&1;
            const int t = row>>5, pp = row&31;
            const i64 grow = (i64)t*PH + pair0 + pp;
            uint4 ob = *(const uint4*)(Au8 + grow*512 + k0 + half*16);
            const u8* pbb = (const u8*)&ob;
            *(uint4*)(smA + swz(row, half*32))    = expand8(pbb);
            *(uint4*)(smA + swz(row, half*32+16)) = expand8(pbb+8);
        }
        #pragma unroll
        for (int j=0;j<2;j++){
            int cid = tid + j*256;
            int col = cid>>2, c = cid&3;
            uint4 d = *(const uint4*)(WT + (i64)(c0+col)*512 + k0 + c*8);
            *(uint4*)(smB + swz(col, c*16)) = d;
        }
        __syncthreads();
        bf16x8 bfr[4];
        #pragma unroll
        for (int cf=0;cf<4;cf++)
            bfr[cf] = *(const bf16x8*)(smB + swz(wn*64 + cf*16 + ln, g*16));
        #pragma unroll
        for (int t=0;t<TT;t++){
            bf16x8 afr = *(const bf16x8*)(smA + swz(t*32 + wm*16 + ln, g*16));
            #pragma unroll
            for (int cf=0;cf<4;cf++)
                acc[t][cf] = MFMA(afr, bfr[cf], acc[t][cf]);
        }
    }

    __syncthreads();
    u8* tile = (u8*)smem;
    #pragma unroll
    for (int cf=0;cf<4;cf++){
        const int c = c0 + wn*64 + cf*16 + ln;
        const float gs  = gw[c] / sqrtf(varw[c] + BNEPS);
        const float bf_ = bias[c], muf = muw[c], bef = bew[c];
        #pragma unroll
        for (int r=0;r<4;r++){
            const int rl = wm*16 + g*4 + r;
            float v = 0.f;
            #pragma unroll
            for (int t=0;t<TT;t++){
                float y = acc[t][cf][r] + bf_;
                float z = (y - muf) * gs + bef;
                v = v + (z - v) * 0.5f;
                float s = ((v - 1.0f) >= 0.f) ? 1.f : 0.f;
                tile[t*4096 + rl*128 + (wn*64 + cf*16 + ln)] = (u8)s;
                v = v * (1.f - s);
            }
        }
    }
    __syncthreads();

    const int pbImg = pbp>>1, rOff = (pbp&1)*128;
    #pragma unroll
    for (int it=0; it<8; it++){
        int task = tid + it*256;
        int kq = task>>9, rem = task&511, gq = rem>>7, rowL = rem&127;
        int rl = rowL>>2, t = rowL&3;
        int ksAbs = nbp*4 + kq;
        int cL = kq*32 + gq*8;
        uint2 ob = *(const uint2*)(tile + t*4096 + rl*128 + cL);
        const u8* pbb = (const u8*)&ob;
        i64 grow = (i64)t*8192 + pairBase + pair0 + rl;
        const float* src = x + grow*512 + ksAbs*32 + gq*8;
        float4 f0 = *(const float4*)src, f1v = *(const float4*)(src+4);
        float vv[8] = {f0.x,f0.y,f0.z,f0.w,f1v.x,f1v.y,f1v.z,f1v.w};
        #pragma unroll
        for (int j=0;j<8;j++) vv[j] = vv[j] + (float)pbb[j];
        u16 h[8];
        #pragma unroll
        for (int j=0;j<8;j++) h[j] = f2bf_rne(vv[j]);
        u8* img = At + ((i64)pbImg*KSW + ksAbs)*16384;
        int off = gq*4096 + (rOff + rowL)*16;
        *(ushort4*)(img + off)     = make_ushort4(h[0],h[1],h[2],h[3]);
        *(ushort4*)(img + off + 8) = make_ushort4(h[4],h[5],h[6],h[7]);
        *(uint2*)(o2g + ((i64)t*PH + pair0 + rl)*512 + ksAbs*32 + gq*8) = ob;
    }
}

// ---------------- spiking attention + attn-LIF (v_th=0.5), qkv packed stride 1536
__global__ __launch_bounds__(256)
void attn_lif_kernel(const u8* __restrict__ qkv, u8* __restrict__ os)
{
    __shared__ __align__(16) char smem[49152];
    char* Kl = smem;
    char* VT = smem + 16384;
    char* AT = smem + 32768;

    const int tid = threadIdx.x;
    const int w = tid>>6, l = tid&63, g = l>>4, ln = l&15;
    const int h = blockIdx.y, b = blockIdx.z;
    const int n0 = blockIdx.x*64 + w*16;

    f32x4 vmem[4];
    #pragma unroll
    for (int cf=0;cf<4;cf++) vmem[cf] = (f32x4)0.f;

    for (int t=0;t<TT;t++){
        const i64 tb = ((i64)(t*16 + b)*256)*1536;
        const i64 ob = ((i64)(t*16 + b)*256)*512 + h*64;
        bf16x8 qf[2];
        #pragma unroll
        for (int ksl=0;ksl<2;ksl++){
            uint2 qv = *(const uint2*)(qkv + tb + (i64)(n0+ln)*1536 + h*64 + ksl*32 + g*8);
            const u8* pb = (const u8*)&qv;
            BF8 f;
            #pragma unroll
            for (int j=0;j<8;j++) f.u[j] = pb[j] ? 0x3F80 : 0;
            qf[ksl] = f.v;
        }
        f32x4 oacc[4];
        #pragma unroll
        for (int cf=0;cf<4;cf++) oacc[cf] = (f32x4)0.f;

        for (int mh=0; mh<2; mh++){
            __syncthreads();
            {
                const int lm = tid>>1, seg = tid&1;
                const u8* src = qkv + tb + (i64)(mh*128+lm)*1536 + 512 + h*64 + seg*32;
                uint4 a = *(const uint4*)(src), c = *(const uint4*)(src+16);
                const u8* pa = (const u8*)&a; const u8* pc = (const u8*)&c;
                #pragma unroll
                for (int q=0;q<4;q++){
                    *(ushort4*)(Kl + swzK(lm, seg*64 + q*8)) =
                        make_ushort4(pa[q*4]?0x3F80:0, pa[q*4+1]?0x3F80:0, pa[q*4+2]?0x3F80:0, pa[q*4+3]?0x3F80:0);
                    *(ushort4*)(Kl + swzK(lm, seg*64 + 32 + q*8)) =
                        make_ushort4(pc[q*4]?0x3F80:0, pc[q*4+1]?0x3F80:0, pc[q*4+2]?0x3F80:0, pc[q*4+3]?0x3F80:0);
                }
            }
            {
                const int lm = tid>>1, seg = tid&1;
                const u8* src = qkv + tb + (i64)(mh*128+lm)*1536 + 1024 + h*64 + seg*32;
                uint4 a = *(const uint4*)(src), c = *(const uint4*)(src+16);
                const u8* pa = (const u8*)&a; const u8* pc = (const u8*)&c;
                #pragma unroll
                for (int j=0;j<16;j++){
                    *(u16*)(VT + swzV(seg*32 + j,      lm*2)) = pa[j] ? 0x3F80 : 0;
                    *(u16*)(VT + swzV(seg*32 + 16 + j, lm*2)) = pc[j] ? 0x3F80 : 0;
                }
            }
            __syncthreads();
            #pragma unroll
            for (int rf=0;rf<8;rf++){
                f32x4 s = (f32x4)0.f;
                #pragma unroll
                for (int ksl=0;ksl<2;ksl++){
                    bf16x8 kf = *(const bf16x8*)(Kl + swzK(rf*16+ln, ksl*64 + g*16));
                    s = MFMA(kf, qf[ksl], s);
                }
                ushort4 pk = make_ushort4(f2bf_rne(s[0]*0.125f), f2bf_rne(s[1]*0.125f),
                                          f2bf_rne(s[2]*0.125f), f2bf_rne(s[3]*0.125f));
                *(ushort4*)(AT + swzV(w*16+ln, rf*32 + g*8)) = pk;
            }
            #pragma unroll
            for (int ms=0;ms<4;ms++){
                bf16x8 af = *(const bf16x8*)(AT + swzV(w*16+ln, ms*64 + g*16));
                #pragma unroll
                for (int cf=0;cf<4;cf++){
                    bf16x8 vf = *(const bf16x8*)(VT + swzV(cf*16+ln, ms*64 + g*16));
                    oacc[cf] = MFMA(af, vf, oacc[cf]);
                }
            }
        }
        #pragma unroll
        for (int cf=0;cf<4;cf++)
            #pragma unroll
            for (int r=0;r<4;r++){
                float v = vmem[cf][r];
                v = v + (oacc[cf][r] - v) * 0.5f;
                float s = ((v - 0.5f) >= 0.f) ? 1.f : 0.f;
                os[ob + (i64)(n0 + g*4 + r)*512 + cf*16 + ln] = (u8)s;
                vmem[cf][r] = v * (1.f - s);
            }
    }
}

extern "C" void kernel_launch(void* const* d_in, const int* in_sizes, int n_in,
                              void* d_out, int out_size, void* d_ws, size_t ws_size,
                              hipStream_t stream)
{
    (void)in_sizes; (void)n_in; (void)out_size; (void)ws_size;
    const float* x = (const float*)d_in[0];
    #define GETP(i) ((const float*)d_in[i])

    char* ws = (char*)d_ws;
    u8*  Bqkv = (u8*)(ws + 0);               // 12*16*8192 = 1,572,864
    u8*  Bf1  = (u8*)(ws + 1572864);         // 16*16*8192 = 2,097,152
    u8*  Bf2  = (u8*)(ws + 3670016);         //  2*64*16384 = 2,097,152
    u16* WTp  = (u16*)(ws + 5767168);        //  524,288
    u8*  At   = (u8*)(ws + 6291456);         // 64*16*16384 = 16,777,216
    u8*  qkv  = (u8*)(ws + 23068672);        // 25,165,824
    u8*  os_  = (u8*)(ws + 48234496);        //  8,388,608
    u8*  o2h[2] = { (u8*)(ws + 56623104), (u8*)(ws + 65011712) };   // 8,388,608 each
    u8*  hhb[2] = { (u8*)(ws + 73400320), (u8*)(ws + 77594624) };   // 4,194,304 each -> ends 81,788,928

    hipFuncSetAttribute((const void*)gemm8<false>, hipFuncAttributeMaxDynamicSharedMemorySize, 49152);
    hipFuncSetAttribute((const void*)gemm8<true>,  hipFuncAttributeMaxDynamicSharedMemorySize, 49152);

    dim3 blk(256,1,1);
    // W prep: qkv/f1 use 128-col images; f2 keeps 256-col
    wsplit_rne<<<dim3(16,4), blk,0,stream>>>(GETP(1),  Bqkv, 512, 0, 16, 128);
    wsplit_rne<<<dim3(16,4), blk,0,stream>>>(GETP(7),  Bqkv, 512, 4, 16, 128);
    wsplit_rne<<<dim3(16,4), blk,0,stream>>>(GETP(13), Bqkv, 512, 8, 16, 128);
    wsplit_rne<<<dim3(16,16),blk,0,stream>>>(GETP(25), Bf1, 2048, 0, 16, 128);
    wsplit_rne<<<dim3(64,2), blk,0,stream>>>(GETP(31), Bf2,  512, 0, 64, 256);
    wsplit_old<<<dim3(8,8),  blk,0,stream>>>(GETP(19), WTp,  512, 512);

    for (int hb = 0; hb < 2; hb++){
        const int pb = hb * PH;
        asplitT<<<dim3(64,16),blk,0,stream>>>(x, At, pb);
        // fused q/k/v (N=1536, NB=12, grid 768)
        gemm8<false><<<dim3(768),dim3(512),49152,stream>>>(At, Bqkv,
            GETP(2),GETP(8),GETP(14),  GETP(3),GETP(9),GETP(15),
            GETP(4),GETP(10),GETP(16), GETP(5),GETP(11),GETP(17),
            GETP(6),GETP(12),GETP(18), qkv, 12, 1536, 511);
        attn_lif_kernel<<<dim3(4,8,16),blk,0,stream>>>(qkv, os_);
        // p stage + fused o2/f1-image production
        gemm_p<<<dim3(4,128),blk,0,stream>>>(os_, WTp,
            GETP(20),GETP(21),GETP(22),GETP(23),GETP(24), x, o2h[hb], At, pb);
        // f1 (N=2048, NB=16, grid 1024, bitpacked out)
        gemm8<true><<<dim3(1024),dim3(512),49152,stream>>>(At, Bf1,
            GETP(26),GETP(26),GETP(26), GETP(27),GETP(27),GETP(27),
            GETP(28),GETP(28),GETP(28), GETP(29),GETP(29),GETP(29),
            GETP(30),GETP(30),GETP(30), hhb[hb], 16, 2048, 2047);
    }
    // f2 v4: both halves, grid 512, T14 staging, coalesced epilogue -> d_out
    gemm8_f2<<<dim3(512),dim3(512),0,stream>>>(hhb[0], hhb[1], Bf2,
        GETP(32),GETP(33),GETP(34),GETP(35),GETP(36), x, o2h[0], o2h[1], (float*)d_out);
}

// Round 19
// 379.119 us; speedup vs baseline: 3.5587x; 1.0782x over previous
//
#include <hip/hip_runtime.h>

typedef unsigned char u8;
typedef unsigned short u16;
typedef unsigned int u32;
typedef unsigned long long u64;
typedef long long i64;

#define TT 4
#define PH 8192             // pairs (full, no half split)
#define KSW 16              // K/32 images for K=512
#define BNEPS 1e-5f

typedef __attribute__((ext_vector_type(8))) __bf16 bf16x8;
typedef __attribute__((ext_vector_type(4))) float f32x4;

__device__ __forceinline__ float bf2f(u16 b){ return __uint_as_float(((u32)b)<<16); }
__device__ __forceinline__ u16 f2bf_rne(float f){ u32 u = __float_as_uint(f); return (u16)((u + 0x7FFFu + ((u>>16)&1u))>>16); }

__device__ __forceinline__ f32x4 MFMA(bf16x8 a, bf16x8 b, f32x4 c){
    return __builtin_amdgcn_mfma_f32_16x16x32_bf16(a, b, c, 0, 0, 0);
}

union BF8 { u16 u[8]; bf16x8 v; };

__device__ __forceinline__ void gload16(const void* g, void* l){
    __builtin_amdgcn_global_load_lds(
        (const __attribute__((address_space(1))) unsigned int*)g,
        (__attribute__((address_space(3))) unsigned int*)l, 16, 0, 0);
}

// reg-staged kernels' swizzles (validated r3-r18)
__device__ __forceinline__ int swz(int row, int off){ return row*64 + (off ^ (((row>>1)&3)<<4)); }
__device__ __forceinline__ int swzK(int row, int off){ return row*128 + (off ^ ((row&7)<<4)); }
__device__ __forceinline__ int swzV(int row, int off){ return row*256 + (off ^ ((row&7)<<4)); }

__device__ __forceinline__ uint4 expand8(const u8* pb){
    u32 w0 = (pb[0]?0x3F80u:0u) | ((pb[1]?0x3F80u:0u)<<16);
    u32 w1 = (pb[2]?0x3F80u:0u) | ((pb[3]?0x3F80u:0u)<<16);
    u32 w2 = (pb[4]?0x3F80u:0u) | ((pb[5]?0x3F80u:0u)<<16);
    u32 w3 = (pb[6]?0x3F80u:0u) | ((pb[7]?0x3F80u:0u)<<16);
    return make_uint4(w0,w1,w2,w3);
}
__device__ __forceinline__ uint4 expandbits(u32 bits){
    u32 w0 = ((bits>>0)&1?0x3F80u:0u) | ((bits>>1)&1?0x3F800000u:0u);
    u32 w1 = ((bits>>2)&1?0x3F80u:0u) | ((bits>>3)&1?0x3F800000u:0u);
    u32 w2 = ((bits>>4)&1?0x3F80u:0u) | ((bits>>5)&1?0x3F800000u:0u);
    u32 w3 = ((bits>>6)&1?0x3F80u:0u) | ((bits>>7)&1?0x3F800000u:0u);
    return make_uint4(w0,w1,w2,w3);
}

// ---------------- W -> CB-col 1-plane RNE images
__global__ __launch_bounds__(256)
void wsplit_rne(const float* __restrict__ W, u8* __restrict__ out, int NC, int nbOff, int ksn, int CB)
{
    const int ks = blockIdx.x, nbl = blockIdx.y;
    const int c0 = nbl*CB;
    u8* img = out + ((i64)(nbOff+nbl)*ksn + ks)*(i64)(CB*64);
    const int iters = CB >> 6;
    for (int it=0; it<iters; it++){
        int task = threadIdx.x + it*256;
        int col = task>>2, gq = task&3;
        float v[8];
        #pragma unroll
        for (int j=0;j<8;j++) v[j] = W[(i64)(ks*32 + gq*8 + j)*NC + c0 + col];
        u16 h[8];
        #pragma unroll
        for (int j=0;j<8;j++) h[j] = f2bf_rne(v[j]);
        int off = gq*(CB*16) + col*16;
        *(ushort4*)(img + off)     = make_ushort4(h[0],h[1],h[2],h[3]);
        *(ushort4*)(img + off + 8) = make_ushort4(h[4],h[5],h[6],h[7]);
    }
}

// ---------------- W -> RNE bf16 [NC][K] (for p reg-staged GEMM)
__global__ __launch_bounds__(256)
void wsplit_old(const float* __restrict__ W, u16* __restrict__ out, int K, int NC)
{
    __shared__ float tile[64][65];
    const int k0 = blockIdx.x*64, c0 = blockIdx.y*64;
    const int tid = threadIdx.x;
    #pragma unroll
    for (int j=0;j<16;j++){
        int el = tid + j*256; int r = el>>6, c = el&63;
        tile[r][c] = W[(i64)(k0+r)*NC + c0 + c];
    }
    __syncthreads();
    #pragma unroll
    for (int j=0;j<16;j++){
        int el = tid + j*256; int c = el>>6, k = el&63;
        out[(i64)(c0+c)*K + k0 + k] = f2bf_rne(tile[k][c]);
    }
}

// ---------------- x -> A images (1-plane RNE): img(pb,ks)[g][row 0..255][16B], row = pair*4+t, 16KB
__global__ __launch_bounds__(256)
void asplitT(const float* __restrict__ x, u8* __restrict__ At)
{
    const int pb = blockIdx.x, ks = blockIdx.y;     // pb 0..127
    u8* img = At + ((i64)pb*KSW + ks)*16384;
    #pragma unroll
    for (int it=0; it<4; it++){
        int task = threadIdx.x + it*256;
        int row = task>>2, gq = task&3;
        int pair = row>>2, t = row&3;
        i64 grow = (i64)t*PH + pb*64 + pair;
        const float* src = x + grow*512 + ks*32 + gq*8;
        float4 f0 = *(const float4*)src, f1v = *(const float4*)(src+4);
        float vv[8] = {f0.x,f0.y,f0.z,f0.w,f1v.x,f1v.y,f1v.z,f1v.w};
        u16 h[8];
        #pragma unroll
        for (int j=0;j<8;j++) h[j] = f2bf_rne(vv[j]);
        int off = gq*4096 + row*16;
        *(ushort4*)(img + off)     = make_ushort4(h[0],h[1],h[2],h[3]);
        *(ushort4*)(img + off + 8) = make_ushort4(h[4],h[5],h[6],h[7]);
    }
}

// ---------------- gemm8 (1-product RNE(A)*RNE(W)): BM=256 x BN=128,
// dbuf 2x(A 16K + B 8K) = 48KB -> 3 blocks/CU. 8 waves 4Mx2N, 16 MFMA/tile.
template<bool BITOUT>
__global__ __launch_bounds__(512,4)
void gemm8(const u8* __restrict__ At, const u8* __restrict__ Bt,
           const float* __restrict__ b0, const float* __restrict__ b1, const float* __restrict__ b2,
           const float* __restrict__ g0, const float* __restrict__ g1, const float* __restrict__ g2,
           const float* __restrict__ e0, const float* __restrict__ e1, const float* __restrict__ e2,
           const float* __restrict__ u0, const float* __restrict__ u1, const float* __restrict__ u2,
           const float* __restrict__ v0, const float* __restrict__ v1, const float* __restrict__ v2,
           u8* __restrict__ outp, int NB, int NCT, int cmask)
{
    extern __shared__ __align__(16) char smem[];     // 49152: 2 x (A 16K + B 8K)
    const int tid = threadIdx.x;
    const int cpx = gridDim.x >> 3;
    const int serial = (blockIdx.x & 7)*cpx + (blockIdx.x >> 3);
    const int pb = serial / NB, nb = serial % NB;    // pb 0..127

    const int w = tid>>6, lane = tid&63, g = lane>>4, ln = lane&15;
    const int wm = w>>1, wn = w&1;                   // 4M x 2N, wave 64x64

    f32x4 acc[4][4];
    #pragma unroll
    for (int fm=0;fm<4;fm++)
        #pragma unroll
        for (int cb=0;cb<4;cb++) acc[fm][cb] = (f32x4)0.f;

    const u8* Ab = At + (i64)pb*KSW*16384;
    const u8* Bb = Bt + (i64)nb*KSW*8192;

    #pragma unroll
    for (int j=0;j<2;j++)
        gload16(Ab + j*8192 + tid*16, smem + j*8192 + tid*16);
    gload16(Bb + tid*16, smem + 16384 + tid*16);
    __syncthreads();

    for (int ks=0; ks<KSW; ks++){
        char* cur = smem + (ks&1)*24576;
        char* nxt = smem + ((ks+1)&1)*24576;
        if (ks+1 < KSW){
            const u8* Ai = Ab + (i64)(ks+1)*16384;
            #pragma unroll
            for (int j=0;j<2;j++) gload16(Ai + j*8192 + tid*16, nxt + j*8192 + tid*16);
            gload16(Bb + (i64)(ks+1)*8192 + tid*16, nxt + 16384 + tid*16);
        }
        bf16x8 bfr[4];
        #pragma unroll
        for (int cb=0;cb<4;cb++){
            int col = wn*64 + cb*16 + ln;
            bfr[cb] = *(const bf16x8*)(cur + 16384 + g*2048 + col*16);
        }
        bf16x8 af[4];
        #pragma unroll
        for (int fm=0; fm<4; fm++){
            int row = wm*64 + fm*16 + ln;
            af[fm] = *(const bf16x8*)(cur + g*4096 + row*16);
        }
        __builtin_amdgcn_s_setprio(1);
        #pragma unroll
        for (int fm=0; fm<4; fm++)
            #pragma unroll
            for (int cb=0;cb<4;cb++)
                acc[fm][cb] = MFMA(af[fm], bfr[cb], acc[fm][cb]);
        __builtin_amdgcn_s_setprio(0);
        __syncthreads();
    }

    if (BITOUT){
        #pragma unroll
        for (int cb=0; cb<4; cb++){
            const int c = nb*128 + wn*64 + cb*16 + ln;
            const float gs  = g0[c & cmask] / sqrtf(v0[c & cmask] + BNEPS);
            const float bf_ = b0[c & cmask], muf = u0[c & cmask], bef = e0[c & cmask];
            #pragma unroll
            for (int fm=0; fm<4; fm++){
                const int prow = pb*64 + wm*16 + fm*4 + g;
                float v = 0.f;
                #pragma unroll
                for (int t=0; t<TT; t++){
                    float y = acc[fm][cb][t] + bf_;
                    float z = (y - muf) * gs + bef;
                    v = v + (z - v) * 0.5f;
                    float s = ((v - 1.0f) >= 0.f) ? 1.f : 0.f;
                    u64 bal = __ballot(s != 0.f);
                    if (ln == 0)
                        *(u16*)(outp + (i64)(t*PH + prow)*(NCT>>3) + ((nb*128 + wn*64 + cb*16)>>3)) = (u16)(bal >> (g*16));
                    v = v * (1.f - s);
                }
            }
        }
    } else {
        // LDS-staged coalesced epilogue: tile [t][64 rows][128 c] u8 = 32KB (fits 48KB)
        u8* tile = (u8*)smem;
        #pragma unroll
        for (int cb=0; cb<4; cb++){
            const int c = nb*128 + wn*64 + cb*16 + ln;
            int which = c >> 9; if (which > 2) which = 2;
            const float* bp = which==0?b0:(which==1?b1:b2);
            const float* gp = which==0?g0:(which==1?g1:g2);
            const float* ep = which==0?e0:(which==1?e1:e2);
            const float* up = which==0?u0:(which==1?u1:u2);
            const float* vp = which==0?v0:(which==1?v1:v2);
            const int ci = c & cmask;
            const float gs  = gp[ci] / sqrtf(vp[ci] + BNEPS);
            const float bf_ = bp[ci], muf = up[ci], bef = ep[ci];
            #pragma unroll
            for (int fm=0; fm<4; fm++){
                const int rowL = wm*16 + fm*4 + g;
                float v = 0.f;
                #pragma unroll
                for (int t=0; t<TT; t++){
                    float y = acc[fm][cb][t] + bf_;
                    float z = (y - muf) * gs + bef;
                    v = v + (z - v) * 0.5f;
                    float s = ((v - 1.0f) >= 0.f) ? 1.f : 0.f;
                    tile[t*8192 + rowL*128 + (wn*64 + cb*16 + ln)] = (u8)s;
                    v = v * (1.f - s);
                }
            }
        }
        __syncthreads();
        #pragma unroll
        for (int it=0; it<4; it++){
            int task = tid + it*512;
            int t = task>>9, row = (task>>3)&63, seg = task&7;
            uint4 d = *(const uint4*)(tile + t*8192 + row*128 + seg*16);
            *(uint4*)(outp + (i64)(t*PH + pb*64 + row)*NCT + nb*128 + seg*16) = d;
        }
    }
}

// ---------------- f2: BM=128 x BN=256, K=2048, grid 512, T14 staging, full-size (no half mux),
// LDS-transpose coalesced epilogue (float4 x/out, u32 o2).
__global__ __launch_bounds__(512,4)
void gemm8_f2(const u8* __restrict__ Abits, const u8* __restrict__ Bt,
              const float* __restrict__ bias, const float* __restrict__ gw,
              const float* __restrict__ bew,  const float* __restrict__ muw,
              const float* __restrict__ varw,
              const float* __restrict__ x, const u8* __restrict__ o2g,
              float* __restrict__ outF)
{
    __shared__ __align__(16) char smem[49152];
    const int tid = threadIdx.x;
    const int cpx = gridDim.x >> 3;
    const int serial = (blockIdx.x & 7)*cpx + (blockIdx.x >> 3);
    const int nb = serial & 1, pbg = serial >> 1;    // pbg 0..255

    const int w = tid>>6, lane = tid&63, g = lane>>4, ln = lane&15;
    const int wm = w>>2, wn = w&3;

    f32x4 acc[4][4];
    #pragma unroll
    for (int fm=0;fm<4;fm++)
        #pragma unroll
        for (int cb=0;cb<4;cb++) acc[fm][cb] = (f32x4)0.f;

    const u8* Bb = Bt + (i64)nb*64*16384;
    const int aRow = tid>>2, aGq = tid&3;
    const i64 aGrow = (i64)(aRow&3)*PH + pbg*32 + (aRow>>2);

    {
        u32 b40 = *(const u32*)(Abits + aGrow*256);
        *(uint4*)(smem + swz(aRow, aGq*16)) = expandbits(b40 >> (8*aGq));
    }
    #pragma unroll
    for (int j=0;j<2;j++)
        gload16(Bb + (tid + j*512)*16, smem + 8192 + (tid + j*512)*16);
    __syncthreads();

    for (int ks=0; ks<64; ks++){
        char* cur = smem + (ks&1)*24576;
        char* nxt = smem + ((ks+1)&1)*24576;
        const bool pre = (ks+1 < 64);
        u32 b4n = 0;
        if (pre){
            b4n = *(const u32*)(Abits + aGrow*256 + (ks+1)*4);
            #pragma unroll
            for (int j=0;j<2;j++)
                gload16(Bb + (i64)(ks+1)*16384 + (tid+j*512)*16, nxt + 8192 + (tid+j*512)*16);
        }
        bf16x8 bfr[4], af[4];
        #pragma unroll
        for (int cb=0;cb<4;cb++)
            bfr[cb] = *(const bf16x8*)(cur + 8192 + g*4096 + (wn*64 + cb*16 + ln)*16);
        #pragma unroll
        for (int fm=0;fm<4;fm++)
            af[fm] = *(const bf16x8*)(cur + swz(wm*64 + fm*16 + ln, g*16));
        __builtin_amdgcn_s_setprio(1);
        #pragma unroll
        for (int fm=0;fm<4;fm++)
            #pragma unroll
            for (int cb=0;cb<4;cb++)
                acc[fm][cb] = MFMA(af[fm], bfr[cb], acc[fm][cb]);
        __builtin_amdgcn_s_setprio(0);
        if (pre)
            *(uint4*)(nxt + swz(aRow, aGq*16)) = expandbits(b4n >> (8*aGq));
        __syncthreads();
    }

    float gsA[4], bfA[4], muA[4], beA[4];
    #pragma unroll
    for (int cb=0;cb<4;cb++){
        const int c = nb*256 + wn*64 + cb*16 + ln;
        gsA[cb] = gw[c] / sqrtf(varw[c] + BNEPS);
        bfA[cb] = bias[c]; muA[cb] = muw[c]; beA[cb] = bew[c];
    }
    float vst[4][4];
    #pragma unroll
    for (int fm=0;fm<4;fm++)
        #pragma unroll
        for (int cb=0;cb<4;cb++) vst[fm][cb] = 0.f;

    float* ft = (float*)smem;
    for (int t=0; t<TT; t++){
        __syncthreads();
        #pragma unroll
        for (int cb=0;cb<4;cb++)
            #pragma unroll
            for (int fm=0;fm<4;fm++){
                const int rowL = wm*16 + fm*4 + g;
                float y = acc[fm][cb][t] + bfA[cb];
                float z = (y - muA[cb]) * gsA[cb] + beA[cb];
                float v = vst[fm][cb];
                v = v + (z - v) * 0.5f;
                float s = ((v - 1.0f) >= 0.f) ? 1.f : 0.f;
                ft[rowL*264 + wn*64 + cb*16 + ln] = s;
                vst[fm][cb] = v * (1.f - s);
            }
        __syncthreads();
        #pragma unroll
        for (int it=0; it<4; it++){
            int task = tid + it*512;
            int rowL = task>>6, seg = task&63;
            float4 sv = *(const float4*)(ft + rowL*264 + seg*4);
            i64 grow = (i64)t*PH + pbg*32 + rowL;
            const int cg = nb*256 + seg*4;
            float4 xv = *(const float4*)(x + grow*512 + cg);
            u32 o4 = *(const u32*)(o2g + grow*512 + cg);
            float4 r;
            r.x = (xv.x + (float)( o4      &255u)) + sv.x;
            r.y = (xv.y + (float)((o4>> 8) &255u)) + sv.y;
            r.z = (xv.z + (float)((o4>>16) &255u)) + sv.z;
            r.w = (xv.w + (float)((o4>>24) &255u)) + sv.w;
            *(float4*)(outF + grow*512 + cg) = r;
        }
    }
}

// ---------------- p stage: spikes x W GEMM + BN + LIF -> o2 (global) + f1 A-images (RNE(x+o2))
__global__ __launch_bounds__(256)
void gemm_p(const u8* __restrict__ Au8, const u16* __restrict__ WT,
            const float* __restrict__ bias, const float* __restrict__ gw,
            const float* __restrict__ bew,  const float* __restrict__ muw,
            const float* __restrict__ varw,
            const float* __restrict__ x, u8* __restrict__ o2g,
            u8* __restrict__ At)
{
    __shared__ __align__(16) char smem[16384];
    char* smA = smem;
    char* smB = smem + 8192;
    const int tid = threadIdx.x;
    const int nbp = blockIdx.x, pbp = blockIdx.y;   // pbp 0..255
    const int c0 = nbp*128, pair0 = pbp*32;
    const int w = tid>>6, l = tid&63, g = l>>4, ln = l&15;
    const int wm = w>>1, wn = w&1;

    f32x4 acc[TT][4];
    #pragma unroll
    for (int t=0;t<TT;t++)
        #pragma unroll
        for (int cf=0;cf<4;cf++) acc[t][cf] = (f32x4)0.f;

    for (int k0 = 0; k0 < 512; k0 += 32){
        __syncthreads();
        {
            const int row = tid>>1, half = tid&1;
            const int t = row>>5, pp = row&31;
            const i64 grow = (i64)t*PH + pair0 + pp;
            uint4 ob = *(const uint4*)(Au8 + grow*512 + k0 + half*16);
            const u8* pbb = (const u8*)&ob;
            *(uint4*)(smA + swz(row, half*32))    = expand8(pbb);
            *(uint4*)(smA + swz(row, half*32+16)) = expand8(pbb+8);
        }
        #pragma unroll
        for (int j=0;j<2;j++){
            int cid = tid + j*256;
            int col = cid>>2, c = cid&3;
            uint4 d = *(const uint4*)(WT + (i64)(c0+col)*512 + k0 + c*8);
            *(uint4*)(smB + swz(col, c*16)) = d;
        }
        __syncthreads();
        bf16x8 bfr[4];
        #pragma unroll
        for (int cf=0;cf<4;cf++)
            bfr[cf] = *(const bf16x8*)(smB + swz(wn*64 + cf*16 + ln, g*16));
        #pragma unroll
        for (int t=0;t<TT;t++){
            bf16x8 afr = *(const bf16x8*)(smA + swz(t*32 + wm*16 + ln, g*16));
            #pragma unroll
            for (int cf=0;cf<4;cf++)
                acc[t][cf] = MFMA(afr, bfr[cf], acc[t][cf]);
        }
    }

    __syncthreads();
    u8* tile = (u8*)smem;
    #pragma unroll
    for (int cf=0;cf<4;cf++){
        const int c = c0 + wn*64 + cf*16 + ln;
        const float gs  = gw[c] / sqrtf(varw[c] + BNEPS);
        const float bf_ = bias[c], muf = muw[c], bef = bew[c];
        #pragma unroll
        for (int r=0;r<4;r++){
            const int rl = wm*16 + g*4 + r;
            float v = 0.f;
            #pragma unroll
            for (int t=0;t<TT;t++){
                float y = acc[t][cf][r] + bf_;
                float z = (y - muf) * gs + bef;
                v = v + (z - v) * 0.5f;
                float s = ((v - 1.0f) >= 0.f) ? 1.f : 0.f;
                tile[t*4096 + rl*128 + (wn*64 + cf*16 + ln)] = (u8)s;
                v = v * (1.f - s);
            }
        }
    }
    __syncthreads();

    const int pbImg = pbp>>1, rOff = (pbp&1)*128;
    #pragma unroll
    for (int it=0; it<8; it++){
        int task = tid + it*256;
        int kq = task>>9, rem = task&511, gq = rem>>7, rowL = rem&127;
        int rl = rowL>>2, t = rowL&3;
        int ksAbs = nbp*4 + kq;
        int cL = kq*32 + gq*8;
        uint2 ob = *(const uint2*)(tile + t*4096 + rl*128 + cL);
        const u8* pbb = (const u8*)&ob;
        i64 grow = (i64)t*PH + pair0 + rl;
        const float* src = x + grow*512 + ksAbs*32 + gq*8;
        float4 f0 = *(const float4*)src, f1v = *(const float4*)(src+4);
        float vv[8] = {f0.x,f0.y,f0.z,f0.w,f1v.x,f1v.y,f1v.z,f1v.w};
        #pragma unroll
        for (int j=0;j<8;j++) vv[j] = vv[j] + (float)pbb[j];
        u16 h[8];
        #pragma unroll
        for (int j=0;j<8;j++) h[j] = f2bf_rne(vv[j]);
        u8* img = At + ((i64)pbImg*KSW + ksAbs)*16384;
        int off = gq*4096 + (rOff + rowL)*16;
        *(ushort4*)(img + off)     = make_ushort4(h[0],h[1],h[2],h[3]);
        *(ushort4*)(img + off + 8) = make_ushort4(h[4],h[5],h[6],h[7]);
        *(uint2*)(o2g + grow*512 + ksAbs*32 + gq*8) = ob;
    }
}

// ---------------- spiking attention + attn-LIF (v_th=0.5), qkv packed stride 1536, full B=32
__global__ __launch_bounds__(256)
void attn_lif_kernel(const u8* __restrict__ qkv, u8* __restrict__ os)
{
    __shared__ __align__(16) char smem[49152];
    char* Kl = smem;
    char* VT = smem + 16384;
    char* AT = smem + 32768;

    const int tid = threadIdx.x;
    const int w = tid>>6, l = tid&63, g = l>>4, ln = l&15;
    const int h = blockIdx.y, b = blockIdx.z;        // b 0..31
    const int n0 = blockIdx.x*64 + w*16;

    f32x4 vmem[4];
    #pragma unroll
    for (int cf=0;cf<4;cf++) vmem[cf] = (f32x4)0.f;

    for (int t=0;t<TT;t++){
        const i64 tb = ((i64)(t*32 + b)*256)*1536;
        const i64 ob = ((i64)(t*32 + b)*256)*512 + h*64;
        bf16x8 qf[2];
        #pragma unroll
        for (int ksl=0;ksl<2;ksl++){
            uint2 qv = *(const uint2*)(qkv + tb + (i64)(n0+ln)*1536 + h*64 + ksl*32 + g*8);
            const u8* pb = (const u8*)&qv;
            BF8 f;
            #pragma unroll
            for (int j=0;j<8;j++) f.u[j] = pb[j] ? 0x3F80 : 0;
            qf[ksl] = f.v;
        }
        f32x4 oacc[4];
        #pragma unroll
        for (int cf=0;cf<4;cf++) oacc[cf] = (f32x4)0.f;

        for (int mh=0; mh<2; mh++){
            __syncthreads();
            {
                const int lm = tid>>1, seg = tid&1;
                const u8* src = qkv + tb + (i64)(mh*128+lm)*1536 + 512 + h*64 + seg*32;
                uint4 a = *(const uint4*)(src), c = *(const uint4*)(src+16);
                const u8* pa = (const u8*)&a; const u8* pc = (const u8*)&c;
                #pragma unroll
                for (int q=0;q<4;q++){
                    *(ushort4*)(Kl + swzK(lm, seg*64 + q*8)) =
                        make_ushort4(pa[q*4]?0x3F80:0, pa[q*4+1]?0x3F80:0, pa[q*4+2]?0x3F80:0, pa[q*4+3]?0x3F80:0);
                    *(ushort4*)(Kl + swzK(lm, seg*64 + 32 + q*8)) =
                        make_ushort4(pc[q*4]?0x3F80:0, pc[q*4+1]?0x3F80:0, pc[q*4+2]?0x3F80:0, pc[q*4+3]?0x3F80:0);
                }
            }
            {
                const int lm = tid>>1, seg = tid&1;
                const u8* src = qkv + tb + (i64)(mh*128+lm)*1536 + 1024 + h*64 + seg*32;
                uint4 a = *(const uint4*)(src), c = *(const uint4*)(src+16);
                const u8* pa = (const u8*)&a; const u8* pc = (const u8*)&c;
                #pragma unroll
                for (int j=0;j<16;j++){
                    *(u16*)(VT + swzV(seg*32 + j,      lm*2)) = pa[j] ? 0x3F80 : 0;
                    *(u16*)(VT + swzV(seg*32 + 16 + j, lm*2)) = pc[j] ? 0x3F80 : 0;
                }
            }
            __syncthreads();
            #pragma unroll
            for (int rf=0;rf<8;rf++){
                f32x4 s = (f32x4)0.f;
                #pragma unroll
                for (int ksl=0;ksl<2;ksl++){
                    bf16x8 kf = *(const bf16x8*)(Kl + swzK(rf*16+ln, ksl*64 + g*16));
                    s = MFMA(kf, qf[ksl], s);
                }
                ushort4 pk = make_ushort4(f2bf_rne(s[0]*0.125f), f2bf_rne(s[1]*0.125f),
                                          f2bf_rne(s[2]*0.125f), f2bf_rne(s[3]*0.125f));
                *(ushort4*)(AT + swzV(w*16+ln, rf*32 + g*8)) = pk;
            }
            #pragma unroll
            for (int ms=0;ms<4;ms++){
                bf16x8 af = *(const bf16x8*)(AT + swzV(w*16+ln, ms*64 + g*16));
                #pragma unroll
                for (int cf=0;cf<4;cf++){
                    bf16x8 vf = *(const bf16x8*)(VT + swzV(cf*16+ln, ms*64 + g*16));
                    oacc[cf] = MFMA(af, vf, oacc[cf]);
                }
            }
        }
        #pragma unroll
        for (int cf=0;cf<4;cf++)
            #pragma unroll
            for (int r=0;r<4;r++){
                float v = vmem[cf][r];
                v = v + (oacc[cf][r] - v) * 0.5f;
                float s = ((v - 0.5f) >= 0.f) ? 1.f : 0.f;
                os[ob + (i64)(n0 + g*4 + r)*512 + cf*16 + ln] = (u8)s;
                vmem[cf][r] = v * (1.f - s);
            }
    }
}

extern "C" void kernel_launch(void* const* d_in, const int* in_sizes, int n_in,
                              void* d_out, int out_size, void* d_ws, size_t ws_size,
                              hipStream_t stream)
{
    (void)in_sizes; (void)n_in; (void)out_size; (void)ws_size;
    const float* x = (const float*)d_in[0];
    #define GETP(i) ((const float*)d_in[i])

    char* ws = (char*)d_ws;
    u8*  Bqkv  = (u8*)(ws + 0);              // 12*16*8192 = 1,572,864
    u8*  Bf1   = (u8*)(ws + 1572864);        // 16*16*8192 = 2,097,152
    u8*  Bf2   = (u8*)(ws + 3670016);        //  2*64*16384 = 2,097,152
    u16* WTp   = (u16*)(ws + 5767168);       //  524,288 -> ends 6,291,456
    u8*  At    = (u8*)(ws + 6291456);        // x-images: 128*16*16384 = 33,554,432 -> ends 39,845,888
    u8*  qkv   = (u8*)(ws + 39845888);       // 50,331,648 -> ends 90,177,536
    u8*  os_   = At;                          // overlay: At dead after qkv GEMM (16,777,216)
    u8*  Aimg2 = qkv;                         // overlay: qkv dead after attn (33,554,432)
    u8*  o2    = (u8*)(ws + 73400320);        // in qkv region after images (16,777,216)
    u8*  hhb   = At;                          // overlay: os dead after p (8,388,608)

    hipFuncSetAttribute((const void*)gemm8<false>, hipFuncAttributeMaxDynamicSharedMemorySize, 49152);
    hipFuncSetAttribute((const void*)gemm8<true>,  hipFuncAttributeMaxDynamicSharedMemorySize, 49152);

    dim3 blk(256,1,1);
    // W prep: qkv/f1 use 128-col images; f2 keeps 256-col
    wsplit_rne<<<dim3(16,4), blk,0,stream>>>(GETP(1),  Bqkv, 512, 0, 16, 128);
    wsplit_rne<<<dim3(16,4), blk,0,stream>>>(GETP(7),  Bqkv, 512, 4, 16, 128);
    wsplit_rne<<<dim3(16,4), blk,0,stream>>>(GETP(13), Bqkv, 512, 8, 16, 128);
    wsplit_rne<<<dim3(16,16),blk,0,stream>>>(GETP(25), Bf1, 2048, 0, 16, 128);
    wsplit_rne<<<dim3(64,2), blk,0,stream>>>(GETP(31), Bf2,  512, 0, 64, 256);
    wsplit_old<<<dim3(8,8),  blk,0,stream>>>(GETP(19), WTp,  512, 512);

    // full-size pipeline (no half split)
    asplitT<<<dim3(128,16),blk,0,stream>>>(x, At);
    // fused q/k/v (N=1536, NB=12, grid 1536)
    gemm8<false><<<dim3(1536),dim3(512),49152,stream>>>(At, Bqkv,
        GETP(2),GETP(8),GETP(14),  GETP(3),GETP(9),GETP(15),
        GETP(4),GETP(10),GETP(16), GETP(5),GETP(11),GETP(17),
        GETP(6),GETP(12),GETP(18), qkv, 12, 1536, 511);
    attn_lif_kernel<<<dim3(4,8,32),blk,0,stream>>>(qkv, os_);
    // p stage + fused o2/f1-image production (grid (4,256))
    gemm_p<<<dim3(4,256),blk,0,stream>>>(os_, WTp,
        GETP(20),GETP(21),GETP(22),GETP(23),GETP(24), x, o2, Aimg2);
    // f1 (N=2048, NB=16, grid 2048, bitpacked out)
    gemm8<true><<<dim3(2048),dim3(512),49152,stream>>>(Aimg2, Bf1,
        GETP(26),GETP(26),GETP(26), GETP(27),GETP(27),GETP(27),
        GETP(28),GETP(28),GETP(28), GETP(29),GETP(29),GETP(29),
        GETP(30),GETP(30),GETP(30), hhb, 16, 2048, 2047);
    // f2: grid 512, T14 staging, coalesced epilogue -> d_out
    gemm8_f2<<<dim3(512),dim3(512),0,stream>>>(hhb, Bf2,
        GETP(32),GETP(33),GETP(34),GETP(35),GETP(36), x, o2, (float*)d_out);
}

// Round 20
// 377.126 us; speedup vs baseline: 3.5775x; 1.0053x over previous
//
#include <hip/hip_runtime.h>

typedef unsigned char u8;
typedef unsigned short u16;
typedef unsigned int u32;
typedef unsigned long long u64;
typedef long long i64;

#define TT 4
#define PH 8192             // pairs (full, no half split)
#define KSW 16              // K/32 images for K=512
#define BNEPS 1e-5f

typedef __attribute__((ext_vector_type(8))) __bf16 bf16x8;
typedef __attribute__((ext_vector_type(4))) float f32x4;

__device__ __forceinline__ float bf2f(u16 b){ return __uint_as_float(((u32)b)<<16); }
__device__ __forceinline__ u16 f2bf_rne(float f){ u32 u = __float_as_uint(f); return (u16)((u + 0x7FFFu + ((u>>16)&1u))>>16); }

__device__ __forceinline__ f32x4 MFMA(bf16x8 a, bf16x8 b, f32x4 c){
    return __builtin_amdgcn_mfma_f32_16x16x32_bf16(a, b, c, 0, 0, 0);
}

union BF8 { u16 u[8]; bf16x8 v; };

__device__ __forceinline__ void gload16(const void* g, void* l){
    __builtin_amdgcn_global_load_lds(
        (const __attribute__((address_space(1))) unsigned int*)g,
        (__attribute__((address_space(3))) unsigned int*)l, 16, 0, 0);
}

// reg-staged kernels' swizzles (validated r3-r19)
__device__ __forceinline__ int swz(int row, int off){ return row*64 + (off ^ (((row>>1)&3)<<4)); }
__device__ __forceinline__ int swzK(int row, int off){ return row*128 + (off ^ ((row&7)<<4)); }
__device__ __forceinline__ int swzV(int row, int off){ return row*256 + (off ^ ((row&7)<<4)); }

__device__ __forceinline__ uint4 expand8(const u8* pb){
    u32 w0 = (pb[0]?0x3F80u:0u) | ((pb[1]?0x3F80u:0u)<<16);
    u32 w1 = (pb[2]?0x3F80u:0u) | ((pb[3]?0x3F80u:0u)<<16);
    u32 w2 = (pb[4]?0x3F80u:0u) | ((pb[5]?0x3F80u:0u)<<16);
    u32 w3 = (pb[6]?0x3F80u:0u) | ((pb[7]?0x3F80u:0u)<<16);
    return make_uint4(w0,w1,w2,w3);
}
__device__ __forceinline__ uint4 expandbits(u32 bits){
    u32 w0 = ((bits>>0)&1?0x3F80u:0u) | ((bits>>1)&1?0x3F800000u:0u);
    u32 w1 = ((bits>>2)&1?0x3F80u:0u) | ((bits>>3)&1?0x3F800000u:0u);
    u32 w2 = ((bits>>4)&1?0x3F80u:0u) | ((bits>>5)&1?0x3F800000u:0u);
    u32 w3 = ((bits>>6)&1?0x3F80u:0u) | ((bits>>7)&1?0x3F800000u:0u);
    return make_uint4(w0,w1,w2,w3);
}

// ---------------- W -> CB-col 1-plane RNE images
__global__ __launch_bounds__(256)
void wsplit_rne(const float* __restrict__ W, u8* __restrict__ out, int NC, int nbOff, int ksn, int CB)
{
    const int ks = blockIdx.x, nbl = blockIdx.y;
    const int c0 = nbl*CB;
    u8* img = out + ((i64)(nbOff+nbl)*ksn + ks)*(i64)(CB*64);
    const int iters = CB >> 6;
    for (int it=0; it<iters; it++){
        int task = threadIdx.x + it*256;
        int col = task>>2, gq = task&3;
        float v[8];
        #pragma unroll
        for (int j=0;j<8;j++) v[j] = W[(i64)(ks*32 + gq*8 + j)*NC + c0 + col];
        u16 h[8];
        #pragma unroll
        for (int j=0;j<8;j++) h[j] = f2bf_rne(v[j]);
        int off = gq*(CB*16) + col*16;
        *(ushort4*)(img + off)     = make_ushort4(h[0],h[1],h[2],h[3]);
        *(ushort4*)(img + off + 8) = make_ushort4(h[4],h[5],h[6],h[7]);
    }
}

// ---------------- q/k/v W -> 128-col images in ONE launch (blockIdx.z selects W)
__global__ __launch_bounds__(256)
void wsplit_rne3(const float* __restrict__ W0, const float* __restrict__ W1,
                 const float* __restrict__ W2, u8* __restrict__ out)
{
    const int ks = blockIdx.x, nbl = blockIdx.y, z = blockIdx.z;
    const float* W = (z==0) ? W0 : (z==1 ? W1 : W2);
    const int c0 = nbl*128;
    u8* img = out + ((i64)(z*4+nbl)*KSW + ks)*8192;
    #pragma unroll
    for (int it=0; it<2; it++){
        int task = threadIdx.x + it*256;
        int col = task>>2, gq = task&3;
        float v[8];
        #pragma unroll
        for (int j=0;j<8;j++) v[j] = W[(i64)(ks*32 + gq*8 + j)*512 + c0 + col];
        u16 h[8];
        #pragma unroll
        for (int j=0;j<8;j++) h[j] = f2bf_rne(v[j]);
        int off = gq*2048 + col*16;
        *(ushort4*)(img + off)     = make_ushort4(h[0],h[1],h[2],h[3]);
        *(ushort4*)(img + off + 8) = make_ushort4(h[4],h[5],h[6],h[7]);
    }
}

// ---------------- W -> RNE bf16 [NC][K] (for p reg-staged GEMM)
__global__ __launch_bounds__(256)
void wsplit_old(const float* __restrict__ W, u16* __restrict__ out, int K, int NC)
{
    __shared__ float tile[64][65];
    const int k0 = blockIdx.x*64, c0 = blockIdx.y*64;
    const int tid = threadIdx.x;
    #pragma unroll
    for (int j=0;j<16;j++){
        int el = tid + j*256; int r = el>>6, c = el&63;
        tile[r][c] = W[(i64)(k0+r)*NC + c0 + c];
    }
    __syncthreads();
    #pragma unroll
    for (int j=0;j<16;j++){
        int el = tid + j*256; int c = el>>6, k = el&63;
        out[(i64)(c0+c)*K + k0 + k] = f2bf_rne(tile[k][c]);
    }
}

// ---------------- x -> A images (1-plane RNE): img(pb,ks)[g][row 0..255][16B], row = pair*4+t, 16KB
__global__ __launch_bounds__(256)
void asplitT(const float* __restrict__ x, u8* __restrict__ At)
{
    const int pb = blockIdx.x, ks = blockIdx.y;     // pb 0..127
    u8* img = At + ((i64)pb*KSW + ks)*16384;
    #pragma unroll
    for (int it=0; it<4; it++){
        int task = threadIdx.x + it*256;
        int row = task>>2, gq = task&3;
        int pair = row>>2, t = row&3;
        i64 grow = (i64)t*PH + pb*64 + pair;
        const float* src = x + grow*512 + ks*32 + gq*8;
        float4 f0 = *(const float4*)src, f1v = *(const float4*)(src+4);
        float vv[8] = {f0.x,f0.y,f0.z,f0.w,f1v.x,f1v.y,f1v.z,f1v.w};
        u16 h[8];
        #pragma unroll
        for (int j=0;j<8;j++) h[j] = f2bf_rne(vv[j]);
        int off = gq*4096 + row*16;
        *(ushort4*)(img + off)     = make_ushort4(h[0],h[1],h[2],h[3]);
        *(ushort4*)(img + off + 8) = make_ushort4(h[4],h[5],h[6],h[7]);
    }
}

// ---------------- gemm8 (1-product RNE(A)*RNE(W)): BM=256 x BN=128,
// dbuf 2x(A 16K + B 8K) = 48KB -> 3 blocks/CU. 8 waves 4Mx2N, 16 MFMA/tile.
template<bool BITOUT>
__global__ __launch_bounds__(512,4)
void gemm8(const u8* __restrict__ At, const u8* __restrict__ Bt,
           const float* __restrict__ b0, const float* __restrict__ b1, const float* __restrict__ b2,
           const float* __restrict__ g0, const float* __restrict__ g1, const float* __restrict__ g2,
           const float* __restrict__ e0, const float* __restrict__ e1, const float* __restrict__ e2,
           const float* __restrict__ u0, const float* __restrict__ u1, const float* __restrict__ u2,
           const float* __restrict__ v0, const float* __restrict__ v1, const float* __restrict__ v2,
           u8* __restrict__ outp, int NB, int NCT, int cmask)
{
    extern __shared__ __align__(16) char smem[];     // 49152: 2 x (A 16K + B 8K)
    const int tid = threadIdx.x;
    const int cpx = gridDim.x >> 3;
    const int serial = (blockIdx.x & 7)*cpx + (blockIdx.x >> 3);
    const int pb = serial / NB, nb = serial % NB;    // pb 0..127

    const int w = tid>>6, lane = tid&63, g = lane>>4, ln = lane&15;
    const int wm = w>>1, wn = w&1;                   // 4M x 2N, wave 64x64

    f32x4 acc[4][4];
    #pragma unroll
    for (int fm=0;fm<4;fm++)
        #pragma unroll
        for (int cb=0;cb<4;cb++) acc[fm][cb] = (f32x4)0.f;

    const u8* Ab = At + (i64)pb*KSW*16384;
    const u8* Bb = Bt + (i64)nb*KSW*8192;

    #pragma unroll
    for (int j=0;j<2;j++)
        gload16(Ab + j*8192 + tid*16, smem + j*8192 + tid*16);
    gload16(Bb + tid*16, smem + 16384 + tid*16);
    __syncthreads();

    for (int ks=0; ks<KSW; ks++){
        char* cur = smem + (ks&1)*24576;
        char* nxt = smem + ((ks+1)&1)*24576;
        if (ks+1 < KSW){
            const u8* Ai = Ab + (i64)(ks+1)*16384;
            #pragma unroll
            for (int j=0;j<2;j++) gload16(Ai + j*8192 + tid*16, nxt + j*8192 + tid*16);
            gload16(Bb + (i64)(ks+1)*8192 + tid*16, nxt + 16384 + tid*16);
        }
        bf16x8 bfr[4];
        #pragma unroll
        for (int cb=0;cb<4;cb++){
            int col = wn*64 + cb*16 + ln;
            bfr[cb] = *(const bf16x8*)(cur + 16384 + g*2048 + col*16);
        }
        bf16x8 af[4];
        #pragma unroll
        for (int fm=0; fm<4; fm++){
            int row = wm*64 + fm*16 + ln;
            af[fm] = *(const bf16x8*)(cur + g*4096 + row*16);
        }
        __builtin_amdgcn_s_setprio(1);
        #pragma unroll
        for (int fm=0; fm<4; fm++)
            #pragma unroll
            for (int cb=0;cb<4;cb++)
                acc[fm][cb] = MFMA(af[fm], bfr[cb], acc[fm][cb]);
        __builtin_amdgcn_s_setprio(0);
        __syncthreads();
    }

    if (BITOUT){
        #pragma unroll
        for (int cb=0; cb<4; cb++){
            const int c = nb*128 + wn*64 + cb*16 + ln;
            const float gs  = g0[c & cmask] / sqrtf(v0[c & cmask] + BNEPS);
            const float bf_ = b0[c & cmask], muf = u0[c & cmask], bef = e0[c & cmask];
            #pragma unroll
            for (int fm=0; fm<4; fm++){
                const int prow = pb*64 + wm*16 + fm*4 + g;
                float v = 0.f;
                #pragma unroll
                for (int t=0; t<TT; t++){
                    float y = acc[fm][cb][t] + bf_;
                    float z = (y - muf) * gs + bef;
                    v = v + (z - v) * 0.5f;
                    float s = ((v - 1.0f) >= 0.f) ? 1.f : 0.f;
                    u64 bal = __ballot(s != 0.f);
                    if (ln == 0)
                        *(u16*)(outp + (i64)(t*PH + prow)*(NCT>>3) + ((nb*128 + wn*64 + cb*16)>>3)) = (u16)(bal >> (g*16));
                    v = v * (1.f - s);
                }
            }
        }
    } else {
        // LDS-staged coalesced epilogue: tile [t][64 rows][128 c] u8 = 32KB (fits 48KB)
        u8* tile = (u8*)smem;
        #pragma unroll
        for (int cb=0; cb<4; cb++){
            const int c = nb*128 + wn*64 + cb*16 + ln;
            int which = c >> 9; if (which > 2) which = 2;
            const float* bp = which==0?b0:(which==1?b1:b2);
            const float* gp = which==0?g0:(which==1?g1:g2);
            const float* ep = which==0?e0:(which==1?e1:e2);
            const float* up = which==0?u0:(which==1?u1:u2);
            const float* vp = which==0?v0:(which==1?v1:v2);
            const int ci = c & cmask;
            const float gs  = gp[ci] / sqrtf(vp[ci] + BNEPS);
            const float bf_ = bp[ci], muf = up[ci], bef = ep[ci];
            #pragma unroll
            for (int fm=0; fm<4; fm++){
                const int rowL = wm*16 + fm*4 + g;
                float v = 0.f;
                #pragma unroll
                for (int t=0; t<TT; t++){
                    float y = acc[fm][cb][t] + bf_;
                    float z = (y - muf) * gs + bef;
                    v = v + (z - v) * 0.5f;
                    float s = ((v - 1.0f) >= 0.f) ? 1.f : 0.f;
                    tile[t*8192 + rowL*128 + (wn*64 + cb*16 + ln)] = (u8)s;
                    v = v * (1.f - s);
                }
            }
        }
        __syncthreads();
        #pragma unroll
        for (int it=0; it<4; it++){
            int task = tid + it*512;
            int t = task>>9, row = (task>>3)&63, seg = task&7;
            uint4 d = *(const uint4*)(tile + t*8192 + row*128 + seg*16);
            *(uint4*)(outp + (i64)(t*PH + pb*64 + row)*NCT + nb*128 + seg*16) = d;
        }
    }
}

// ---------------- f2: BM=128 x BN=256, K=2048, grid 512, T14 staging,
// LDS-transpose coalesced epilogue (float4 x/out, u32 o2).
__global__ __launch_bounds__(512,4)
void gemm8_f2(const u8* __restrict__ Abits, const u8* __restrict__ Bt,
              const float* __restrict__ bias, const float* __restrict__ gw,
              const float* __restrict__ bew,  const float* __restrict__ muw,
              const float* __restrict__ varw,
              const float* __restrict__ x, const u8* __restrict__ o2g,
              float* __restrict__ outF)
{
    __shared__ __align__(16) char smem[49152];
    const int tid = threadIdx.x;
    const int cpx = gridDim.x >> 3;
    const int serial = (blockIdx.x & 7)*cpx + (blockIdx.x >> 3);
    const int nb = serial & 1, pbg = serial >> 1;    // pbg 0..255

    const int w = tid>>6, lane = tid&63, g = lane>>4, ln = lane&15;
    const int wm = w>>2, wn = w&3;

    f32x4 acc[4][4];
    #pragma unroll
    for (int fm=0;fm<4;fm++)
        #pragma unroll
        for (int cb=0;cb<4;cb++) acc[fm][cb] = (f32x4)0.f;

    const u8* Bb = Bt + (i64)nb*64*16384;
    const int aRow = tid>>2, aGq = tid&3;
    const i64 aGrow = (i64)(aRow&3)*PH + pbg*32 + (aRow>>2);

    {
        u32 b40 = *(const u32*)(Abits + aGrow*256);
        *(uint4*)(smem + swz(aRow, aGq*16)) = expandbits(b40 >> (8*aGq));
    }
    #pragma unroll
    for (int j=0;j<2;j++)
        gload16(Bb + (tid + j*512)*16, smem + 8192 + (tid + j*512)*16);
    __syncthreads();

    for (int ks=0; ks<64; ks++){
        char* cur = smem + (ks&1)*24576;
        char* nxt = smem + ((ks+1)&1)*24576;
        const bool pre = (ks+1 < 64);
        u32 b4n = 0;
        if (pre){
            b4n = *(const u32*)(Abits + aGrow*256 + (ks+1)*4);
            #pragma unroll
            for (int j=0;j<2;j++)
                gload16(Bb + (i64)(ks+1)*16384 + (tid+j*512)*16, nxt + 8192 + (tid+j*512)*16);
        }
        bf16x8 bfr[4], af[4];
        #pragma unroll
        for (int cb=0;cb<4;cb++)
            bfr[cb] = *(const bf16x8*)(cur + 8192 + g*4096 + (wn*64 + cb*16 + ln)*16);
        #pragma unroll
        for (int fm=0;fm<4;fm++)
            af[fm] = *(const bf16x8*)(cur + swz(wm*64 + fm*16 + ln, g*16));
        __builtin_amdgcn_s_setprio(1);
        #pragma unroll
        for (int fm=0;fm<4;fm++)
            #pragma unroll
            for (int cb=0;cb<4;cb++)
                acc[fm][cb] = MFMA(af[fm], bfr[cb], acc[fm][cb]);
        __builtin_amdgcn_s_setprio(0);
        if (pre)
            *(uint4*)(nxt + swz(aRow, aGq*16)) = expandbits(b4n >> (8*aGq));
        __syncthreads();
    }

    float gsA[4], bfA[4], muA[4], beA[4];
    #pragma unroll
    for (int cb=0;cb<4;cb++){
        const int c = nb*256 + wn*64 + cb*16 + ln;
        gsA[cb] = gw[c] / sqrtf(varw[c] + BNEPS);
        bfA[cb] = bias[c]; muA[cb] = muw[c]; beA[cb] = bew[c];
    }
    float vst[4][4];
    #pragma unroll
    for (int fm=0;fm<4;fm++)
        #pragma unroll
        for (int cb=0;cb<4;cb++) vst[fm][cb] = 0.f;

    float* ft = (float*)smem;
    for (int t=0; t<TT; t++){
        __syncthreads();
        #pragma unroll
        for (int cb=0;cb<4;cb++)
            #pragma unroll
            for (int fm=0;fm<4;fm++){
                const int rowL = wm*16 + fm*4 + g;
                float y = acc[fm][cb][t] + bfA[cb];
                float z = (y - muA[cb]) * gsA[cb] + beA[cb];
                float v = vst[fm][cb];
                v = v + (z - v) * 0.5f;
                float s = ((v - 1.0f) >= 0.f) ? 1.f : 0.f;
                ft[rowL*264 + wn*64 + cb*16 + ln] = s;
                vst[fm][cb] = v * (1.f - s);
            }
        __syncthreads();
        #pragma unroll
        for (int it=0; it<4; it++){
            int task = tid + it*512;
            int rowL = task>>6, seg = task&63;
            float4 sv = *(const float4*)(ft + rowL*264 + seg*4);
            i64 grow = (i64)t*PH + pbg*32 + rowL;
            const int cg = nb*256 + seg*4;
            float4 xv = *(const float4*)(x + grow*512 + cg);
            u32 o4 = *(const u32*)(o2g + grow*512 + cg);
            float4 r;
            r.x = (xv.x + (float)( o4      &255u)) + sv.x;
            r.y = (xv.y + (float)((o4>> 8) &255u)) + sv.y;
            r.z = (xv.z + (float)((o4>>16) &255u)) + sv.z;
            r.w = (xv.w + (float)((o4>>24) &255u)) + sv.w;
            *(float4*)(outF + grow*512 + cg) = r;
        }
    }
}

// ---------------- p stage: spikes x W GEMM + BN + LIF -> o2 (global) + f1 A-images (RNE(x+o2))
__global__ __launch_bounds__(256)
void gemm_p(const u8* __restrict__ Au8, const u16* __restrict__ WT,
            const float* __restrict__ bias, const float* __restrict__ gw,
            const float* __restrict__ bew,  const float* __restrict__ muw,
            const float* __restrict__ varw,
            const float* __restrict__ x, u8* __restrict__ o2g,
            u8* __restrict__ At)
{
    __shared__ __align__(16) char smem[16384];
    char* smA = smem;
    char* smB = smem + 8192;
    const int tid = threadIdx.x;
    const int nbp = blockIdx.x, pbp = blockIdx.y;   // pbp 0..255
    const int c0 = nbp*128, pair0 = pbp*32;
    const int w = tid>>6, l = tid&63, g = l>>4, ln = l&15;
    const int wm = w>>1, wn = w&1;

    f32x4 acc[TT][4];
    #pragma unroll
    for (int t=0;t<TT;t++)
        #pragma unroll
        for (int cf=0;cf<4;cf++) acc[t][cf] = (f32x4)0.f;

    for (int k0 = 0; k0 < 512; k0 += 32){
        __syncthreads();
        {
            const int row = tid>>1, half = tid&1;
            const int t = row>>5, pp = row&31;
            const i64 grow = (i64)t*PH + pair0 + pp;
            uint4 ob = *(const uint4*)(Au8 + grow*512 + k0 + half*16);
            const u8* pbb = (const u8*)&ob;
            *(uint4*)(smA + swz(row, half*32))    = expand8(pbb);
            *(uint4*)(smA + swz(row, half*32+16)) = expand8(pbb+8);
        }
        #pragma unroll
        for (int j=0;j<2;j++){
            int cid = tid + j*256;
            int col = cid>>2, c = cid&3;
            uint4 d = *(const uint4*)(WT + (i64)(c0+col)*512 + k0 + c*8);
            *(uint4*)(smB + swz(col, c*16)) = d;
        }
        __syncthreads();
        bf16x8 bfr[4];
        #pragma unroll
        for (int cf=0;cf<4;cf++)
            bfr[cf] = *(const bf16x8*)(smB + swz(wn*64 + cf*16 + ln, g*16));
        #pragma unroll
        for (int t=0;t<TT;t++){
            bf16x8 afr = *(const bf16x8*)(smA + swz(t*32 + wm*16 + ln, g*16));
            #pragma unroll
            for (int cf=0;cf<4;cf++)
                acc[t][cf] = MFMA(afr, bfr[cf], acc[t][cf]);
        }
    }

    __syncthreads();
    u8* tile = (u8*)smem;
    #pragma unroll
    for (int cf=0;cf<4;cf++){
        const int c = c0 + wn*64 + cf*16 + ln;
        const float gs  = gw[c] / sqrtf(varw[c] + BNEPS);
        const float bf_ = bias[c], muf = muw[c], bef = bew[c];
        #pragma unroll
        for (int r=0;r<4;r++){
            const int rl = wm*16 + g*4 + r;
            float v = 0.f;
            #pragma unroll
            for (int t=0;t<TT;t++){
                float y = acc[t][cf][r] + bf_;
                float z = (y - muf) * gs + bef;
                v = v + (z - v) * 0.5f;
                float s = ((v - 1.0f) >= 0.f) ? 1.f : 0.f;
                tile[t*4096 + rl*128 + (wn*64 + cf*16 + ln)] = (u8)s;
                v = v * (1.f - s);
            }
        }
    }
    __syncthreads();

    const int pbImg = pbp>>1, rOff = (pbp&1)*128;
    #pragma unroll
    for (int it=0; it<8; it++){
        int task = tid + it*256;
        int kq = task>>9, rem = task&511, gq = rem>>7, rowL = rem&127;
        int rl = rowL>>2, t = rowL&3;
        int ksAbs = nbp*4 + kq;
        int cL = kq*32 + gq*8;
        uint2 ob = *(const uint2*)(tile + t*4096 + rl*128 + cL);
        const u8* pbb = (const u8*)&ob;
        i64 grow = (i64)t*PH + pair0 + rl;
        const float* src = x + grow*512 + ksAbs*32 + gq*8;
        float4 f0 = *(const float4*)src, f1v = *(const float4*)(src+4);
        float vv[8] = {f0.x,f0.y,f0.z,f0.w,f1v.x,f1v.y,f1v.z,f1v.w};
        #pragma unroll
        for (int j=0;j<8;j++) vv[j] = vv[j] + (float)pbb[j];
        u16 h[8];
        #pragma unroll
        for (int j=0;j<8;j++) h[j] = f2bf_rne(vv[j]);
        u8* img = At + ((i64)pbImg*KSW + ksAbs)*16384;
        int off = gq*4096 + (rOff + rowL)*16;
        *(ushort4*)(img + off)     = make_ushort4(h[0],h[1],h[2],h[3]);
        *(ushort4*)(img + off + 8) = make_ushort4(h[4],h[5],h[6],h[7]);
        *(uint2*)(o2g + grow*512 + ksAbs*32 + gq*8) = ob;
    }
}

// ---------------- spiking attention + attn-LIF (v_th=0.5), qkv packed stride 1536, full B=32
__global__ __launch_bounds__(256)
void attn_lif_kernel(const u8* __restrict__ qkv, u8* __restrict__ os)
{
    __shared__ __align__(16) char smem[49152];
    char* Kl = smem;
    char* VT = smem + 16384;
    char* AT = smem + 32768;

    const int tid = threadIdx.x;
    const int w = tid>>6, l = tid&63, g = l>>4, ln = l&15;
    const int h = blockIdx.y, b = blockIdx.z;        // b 0..31
    const int n0 = blockIdx.x*64 + w*16;

    f32x4 vmem[4];
    #pragma unroll
    for (int cf=0;cf<4;cf++) vmem[cf] = (f32x4)0.f;

    for (int t=0;t<TT;t++){
        const i64 tb = ((i64)(t*32 + b)*256)*1536;
        const i64 ob = ((i64)(t*32 + b)*256)*512 + h*64;
        bf16x8 qf[2];
        #pragma unroll
        for (int ksl=0;ksl<2;ksl++){
            uint2 qv = *(const uint2*)(qkv + tb + (i64)(n0+ln)*1536 + h*64 + ksl*32 + g*8);
            const u8* pb = (const u8*)&qv;
            BF8 f;
            #pragma unroll
            for (int j=0;j<8;j++) f.u[j] = pb[j] ? 0x3F80 : 0;
            qf[ksl] = f.v;
        }
        f32x4 oacc[4];
        #pragma unroll
        for (int cf=0;cf<4;cf++) oacc[cf] = (f32x4)0.f;

        for (int mh=0; mh<2; mh++){
            __syncthreads();
            {
                const int lm = tid>>1, seg = tid&1;
                const u8* src = qkv + tb + (i64)(mh*128+lm)*1536 + 512 + h*64 + seg*32;
                uint4 a = *(const uint4*)(src), c = *(const uint4*)(src+16);
                const u8* pa = (const u8*)&a; const u8* pc = (const u8*)&c;
                #pragma unroll
                for (int q=0;q<4;q++){
                    *(ushort4*)(Kl + swzK(lm, seg*64 + q*8)) =
                        make_ushort4(pa[q*4]?0x3F80:0, pa[q*4+1]?0x3F80:0, pa[q*4+2]?0x3F80:0, pa[q*4+3]?0x3F80:0);
                    *(ushort4*)(Kl + swzK(lm, seg*64 + 32 + q*8)) =
                        make_ushort4(pc[q*4]?0x3F80:0, pc[q*4+1]?0x3F80:0, pc[q*4+2]?0x3F80:0, pc[q*4+3]?0x3F80:0);
                }
            }
            {
                // V transpose staging, vectorized: thread (mq = tid&31, dq = tid>>5)
                // reads 4 V rows (m = mh*128 + mq*4 + i), 8 d's each; writes 8 x ushort4
                // (2-way bank aliasing only). Same values, same VT layout as before.
                const int mq = tid & 31, dq = tid >> 5;
                const u8* src = qkv + tb + (i64)(mh*128 + mq*4)*1536 + 1024 + h*64 + dq*8;
                uint2 r0 = *(const uint2*)(src);
                uint2 r1 = *(const uint2*)(src + 1536);
                uint2 r2 = *(const uint2*)(src + 3072);
                uint2 r3 = *(const uint2*)(src + 4608);
                const u8* p0 = (const u8*)&r0; const u8* p1 = (const u8*)&r1;
                const u8* p2 = (const u8*)&r2; const u8* p3 = (const u8*)&r3;
                #pragma unroll
                for (int jj=0;jj<8;jj++){
                    *(ushort4*)(VT + swzV(dq*8 + jj, mq*8)) =
                        make_ushort4(p0[jj]?0x3F80:0, p1[jj]?0x3F80:0, p2[jj]?0x3F80:0, p3[jj]?0x3F80:0);
                }
            }
            __syncthreads();
            #pragma unroll
            for (int rf=0;rf<8;rf++){
                f32x4 s = (f32x4)0.f;
                #pragma unroll
                for (int ksl=0;ksl<2;ksl++){
                    bf16x8 kf = *(const bf16x8*)(Kl + swzK(rf*16+ln, ksl*64 + g*16));
                    s = MFMA(kf, qf[ksl], s);
                }
                ushort4 pk = make_ushort4(f2bf_rne(s[0]*0.125f), f2bf_rne(s[1]*0.125f),
                                          f2bf_rne(s[2]*0.125f), f2bf_rne(s[3]*0.125f));
                *(ushort4*)(AT + swzV(w*16+ln, rf*32 + g*8)) = pk;
            }
            #pragma unroll
            for (int ms=0;ms<4;ms++){
                bf16x8 af = *(const bf16x8*)(AT + swzV(w*16+ln, ms*64 + g*16));
                #pragma unroll
                for (int cf=0;cf<4;cf++){
                    bf16x8 vf = *(const bf16x8*)(VT + swzV(cf*16+ln, ms*64 + g*16));
                    oacc[cf] = MFMA(af, vf, oacc[cf]);
                }
            }
        }
        #pragma unroll
        for (int cf=0;cf<4;cf++)
            #pragma unroll
            for (int r=0;r<4;r++){
                float v = vmem[cf][r];
                v = v + (oacc[cf][r] - v) * 0.5f;
                float s = ((v - 0.5f) >= 0.f) ? 1.f : 0.f;
                os[ob + (i64)(n0 + g*4 + r)*512 + cf*16 + ln] = (u8)s;
                vmem[cf][r] = v * (1.f - s);
            }
    }
}

extern "C" void kernel_launch(void* const* d_in, const int* in_sizes, int n_in,
                              void* d_out, int out_size, void* d_ws, size_t ws_size,
                              hipStream_t stream)
{
    (void)in_sizes; (void)n_in; (void)out_size; (void)ws_size;
    const float* x = (const float*)d_in[0];
    #define GETP(i) ((const float*)d_in[i])

    char* ws = (char*)d_ws;
    u8*  Bqkv  = (u8*)(ws + 0);              // 12*16*8192 = 1,572,864
    u8*  Bf1   = (u8*)(ws + 1572864);        // 16*16*8192 = 2,097,152
    u8*  Bf2   = (u8*)(ws + 3670016);        //  2*64*16384 = 2,097,152
    u16* WTp   = (u16*)(ws + 5767168);       //  524,288 -> ends 6,291,456
    u8*  At    = (u8*)(ws + 6291456);        // x-images: 128*16*16384 = 33,554,432 -> ends 39,845,888
    u8*  qkv   = (u8*)(ws + 39845888);       // 50,331,648 -> ends 90,177,536
    u8*  os_   = At;                          // overlay: At dead after qkv GEMM (16,777,216)
    u8*  Aimg2 = qkv;                         // overlay: qkv dead after attn (33,554,432)
    u8*  o2    = (u8*)(ws + 73400320);        // in qkv region after images (16,777,216)
    u8*  hhb   = At;                          // overlay: os dead after p (8,388,608)

    hipFuncSetAttribute((const void*)gemm8<false>, hipFuncAttributeMaxDynamicSharedMemorySize, 49152);
    hipFuncSetAttribute((const void*)gemm8<true>,  hipFuncAttributeMaxDynamicSharedMemorySize, 49152);

    dim3 blk(256,1,1);
    // W prep (q/k/v merged into one launch)
    wsplit_rne3<<<dim3(16,4,3),blk,0,stream>>>(GETP(1), GETP(7), GETP(13), Bqkv);
    wsplit_rne<<<dim3(16,16),blk,0,stream>>>(GETP(25), Bf1, 2048, 0, 16, 128);
    wsplit_rne<<<dim3(64,2), blk,0,stream>>>(GETP(31), Bf2,  512, 0, 64, 256);
    wsplit_old<<<dim3(8,8),  blk,0,stream>>>(GETP(19), WTp,  512, 512);

    // full-size pipeline (no half split)
    asplitT<<<dim3(128,16),blk,0,stream>>>(x, At);
    // fused q/k/v (N=1536, NB=12, grid 1536)
    gemm8<false><<<dim3(1536),dim3(512),49152,stream>>>(At, Bqkv,
        GETP(2),GETP(8),GETP(14),  GETP(3),GETP(9),GETP(15),
        GETP(4),GETP(10),GETP(16), GETP(5),GETP(11),GETP(17),
        GETP(6),GETP(12),GETP(18), qkv, 12, 1536, 511);
    attn_lif_kernel<<<dim3(4,8,32),blk,0,stream>>>(qkv, os_);
    // p stage + fused o2/f1-image production (grid (4,256))
    gemm_p<<<dim3(4,256),blk,0,stream>>>(os_, WTp,
        GETP(20),GETP(21),GETP(22),GETP(23),GETP(24), x, o2, Aimg2);
    // f1 (N=2048, NB=16, grid 2048, bitpacked out)
    gemm8<true><<<dim3(2048),dim3(512),49152,stream>>>(Aimg2, Bf1,
        GETP(26),GETP(26),GETP(26), GETP(27),GETP(27),GETP(27),
        GETP(28),GETP(28),GETP(28), GETP(29),GETP(29),GETP(29),
        GETP(30),GETP(30),GETP(30), hhb, 16, 2048, 2047);
    // f2: grid 512, T14 staging, coalesced epilogue -> d_out
    gemm8_f2<<<dim3(512),dim3(512),0,stream>>>(hhb, Bf2,
        GETP(32),GETP(33),GETP(34),GETP(35),GETP(36), x, o2, (float*)d_out);
}